// Round 5
// baseline (90228.375 us; speedup 1.0000x reference)
//
#include <hip/hip_runtime.h>
#include <math.h>

// ---------------- constants ----------------
#define B_    16
#define NT_   197
#define NS_   202
#define HEADS_ 12
#define DEPTH_ 12
#define NCLS_ 100

// ============ block reduce helper (double sum over 256 threads, shfl) ============
__device__ __forceinline__ double block_reduce_sum_d(double s, double* red, int lane, int wid){
#pragma unroll
    for (int off = 32; off; off >>= 1) s += __shfl_xor(s, off);
    if (lane == 0) red[wid] = s;
    __syncthreads();
    double S = red[0] + red[1] + red[2] + red[3];
    __syncthreads();
    return S;
}

// ============ GEMM (full f64): C = A @ W^T + bias (+epilogue) ============
// A: M x K f64, W: N x K f32 (exact weights), C: M x N f64.
// EPI: 0 none, 1 exact GELU, 2 residual add. K%16==0, N%64==0, M guarded.
template<int EPI>
__global__ __launch_bounds__(256) void gemm_dd(
    const double* __restrict__ A, const float* __restrict__ W,
    const float* __restrict__ bias, const double* __restrict__ Res,
    double* __restrict__ C, int M, int K, int N)
{
    __shared__ double As[16][66];
    __shared__ float  Bs[16][68];
    const int tid = threadIdx.x;
    const int tx = tid & 15, ty = tid >> 4;
    const int lc = tid & 15, lr = tid >> 4;
    const long row0 = (long)blockIdx.y * 64;
    const long col0 = (long)blockIdx.x * 64;

    double acc[4][4];
#pragma unroll
    for (int i = 0; i < 4; i++)
#pragma unroll
        for (int j = 0; j < 4; j++) acc[i][j] = 0.0;

    for (int k0 = 0; k0 < K; k0 += 16){
#pragma unroll
        for (int p = 0; p < 4; p++){
            int r = lr + p * 16;
            long gr = row0 + r;
            As[lc][r] = (gr < M) ? A[gr * K + k0 + lc] : 0.0;
            Bs[lc][r] = W[(col0 + r) * K + k0 + lc];
        }
        __syncthreads();
#pragma unroll
        for (int kk = 0; kk < 16; kk++){
            double av[4], bv[4];
#pragma unroll
            for (int i = 0; i < 4; i++) av[i] = As[kk][ty*4+i];
#pragma unroll
            for (int j = 0; j < 4; j++) bv[j] = (double)Bs[kk][tx*4+j];
#pragma unroll
            for (int i = 0; i < 4; i++)
#pragma unroll
                for (int j = 0; j < 4; j++) acc[i][j] += av[i] * bv[j];
        }
        __syncthreads();
    }

#pragma unroll
    for (int i = 0; i < 4; i++){
        long gr = row0 + ty * 4 + i;
        if (gr >= M) continue;
#pragma unroll
        for (int j = 0; j < 4; j++){
            long gc = col0 + tx * 4 + j;
            double v = acc[i][j] + (double)bias[gc];
            if (EPI == 1) v = 0.5 * v * (1.0 + erf(v * 0.70710678118654752440));
            else if (EPI == 2) v += Res[gr * N + gc];
            C[gr * N + gc] = v;
        }
    }
}

// ============ LayerNorm (two-pass, f64) ============
__global__ __launch_bounds__(256) void ln_k(const double* __restrict__ x,
    const float* __restrict__ w, const float* __restrict__ b,
    double* __restrict__ y)
{
    __shared__ double red[4];
    int row = blockIdx.x, t = threadIdx.x;
    int lane = t & 63, wid = t >> 6;
    const double* xr = x + (long)row * 768;
    double v0 = xr[t], v1 = xr[t + 256], v2 = xr[t + 512];
    double S = block_reduce_sum_d(v0 + v1 + v2, red, lane, wid);
    double m = S * (1.0 / 768.0);
    double d0 = v0 - m, d1 = v1 - m, d2 = v2 - m;
    double Q = block_reduce_sum_d(d0*d0 + d1*d1 + d2*d2, red, lane, wid);
    double rs = 1.0 / sqrt(Q * (1.0 / 768.0) + 1e-6);
    double* yr = y + (long)row * 768;
    yr[t]       = d0 * rs * (double)w[t]       + (double)b[t];
    yr[t + 256] = d1 * rs * (double)w[t + 256] + (double)b[t + 256];
    yr[t + 512] = d2 * rs * (double)w[t + 512] + (double)b[t + 512];
}

// ============ DUMB standard MHA: one block per (b,h,n), shared-tree softmax ============
__global__ __launch_bounds__(256) void attn_std_d2(
    const double* __restrict__ qkv, double* __restrict__ o, int Ntok)
{
    __shared__ double q[64];
    __shared__ double p[256];
    __shared__ double red[256];
    int bh = blockIdx.x;
    int b = bh / HEADS_, h = bh % HEADS_;
    int n = blockIdx.y, t = threadIdx.x;
    const long rb = (long)b * Ntok;

    if (t < 64) q[t] = qkv[(rb + n) * 2304 + h * 64 + t] * 0.125;  // q * HD^-0.5
    __syncthreads();

    double s = -1e300;
    if (t < Ntok){
        const double* kr = qkv + (rb + t) * 2304 + 768 + h * 64;
        double a = 0.0;
        for (int j = 0; j < 64; j++) a += q[j] * kr[j];
        s = a;
    }
    red[t] = s; __syncthreads();
    for (int w = 128; w; w >>= 1){ if (t < w) red[t] = fmax(red[t], red[t+w]); __syncthreads(); }
    double mx = red[0]; __syncthreads();
    double e = (t < Ntok) ? exp(s - mx) : 0.0;
    red[t] = e; __syncthreads();
    for (int w = 128; w; w >>= 1){ if (t < w) red[t] += red[t+w]; __syncthreads(); }
    double inv = 1.0 / red[0];
    p[t] = e * inv;
    __syncthreads();

    if (t < 64){
        double a = 0.0;
        for (int m = 0; m < Ntok; m++)
            a += p[m] * qkv[(rb + m) * 2304 + 1536 + h * 64 + t];
        o[(rb + n) * 768 + h * 64 + t] = a;
    }
}

// ============ DUMB deep attention: one block per (b,n); normal-layout output ============
__global__ __launch_bounds__(256) void attn_deep_d2(
    const double* __restrict__ qkv, const float* __restrict__ prompts,
    const int* __restrict__ selm, double* __restrict__ avn, int li)
{
    __shared__ double q[768];
    __shared__ double p[256];
    __shared__ double red[256];
    int b = blockIdx.x, n = blockIdx.y, t = threadIdx.x;

    const double* qr = qkv + (long)(b * NT_ + n) * 2304;
    q[t] = qr[t]; q[t + 256] = qr[t + 256]; q[t + 512] = qr[t + 512];
    __syncthreads();

    const float* kp = prompts + ((long)selm[b] * 6 + 2 * li) * 5 * 768;
    const float* vp = kp + 5 * 768;

    double s = -1e300;
    if (t < 202){
        double a = 0.0;
        if (t < 5){
            const float* kr = kp + t * 768;
            for (int j = 0; j < 768; j++) a += q[j] * (double)kr[j];
        } else {
            const double* kr = qkv + (long)(b * NT_ + (t - 5)) * 2304 + 768;
            for (int j = 0; j < 768; j++) a += q[j] * kr[j];
        }
        s = a * 0.125;   // scores * HD^-0.5 (as reference, post-dot)
    }
    red[t] = s; __syncthreads();
    for (int w = 128; w; w >>= 1){ if (t < w) red[t] = fmax(red[t], red[t+w]); __syncthreads(); }
    double mx = red[0]; __syncthreads();
    double e = (t < 202) ? exp(s - mx) : 0.0;
    red[t] = e; __syncthreads();
    for (int w = 128; w; w >>= 1){ if (t < w) red[t] += red[t+w]; __syncthreads(); }
    double inv = 1.0 / red[0];
    p[t] = e * inv;
    __syncthreads();

    double a0 = 0.0, a1 = 0.0, a2 = 0.0;
    for (int m = 0; m < 5; m++){
        const float* vr = vp + m * 768;
        double pm = p[m];
        a0 += pm * (double)vr[t]; a1 += pm * (double)vr[t + 256]; a2 += pm * (double)vr[t + 512];
    }
    for (int m = 5; m < 202; m++){
        const double* vr = qkv + (long)(b * NT_ + (m - 5)) * 2304 + 1536;
        double pm = p[m];
        a0 += pm * vr[t]; a1 += pm * vr[t + 256]; a2 += pm * vr[t + 512];
    }
    double* orow = avn + (long)(b * NT_ + n) * 768;   // NORMAL (b,n,d) layout
    orow[t] = a0; orow[t + 256] = a1; orow[t + 512] = a2;
}

// ============ explicit scramble: out[b][n'][d'] = avn[b][f%197][f/197], f=n'*768+d' ============
__global__ void scramble_k(const double* __restrict__ avn, double* __restrict__ o){
    long i = (long)blockIdx.x * 256 + threadIdx.x;
    const long per = (long)NT_ * 768;
    long total = (long)B_ * per;
    if (i >= total) return;
    int b = (int)(i / per);
    long f = i - (long)b * per;
    int n = (int)(f % NT_);
    int d = (int)(f / NT_);
    o[i] = avn[(long)b * per + (long)n * 768 + d];
}

// ============ patch unfold (f32 in -> f64 out) ============
__global__ void unfold_k(const float* __restrict__ in, double* __restrict__ out){
    long i = (long)blockIdx.x * 256 + threadIdx.x;
    long total = (long)B_ * 196 * 768;
    if (i >= total) return;
    int f = (int)(i % 768); long rw = i / 768;
    int t = (int)(rw % 196); int b = (int)(rw / 196);
    int gy = t / 14, gx = t % 14;
    int c = f >> 8, rem = f & 255, py = rem >> 4, px = rem & 15;
    out[i] = (double)in[(((long)(b * 3 + c) * 224) + gy * 16 + py) * 224 + gx * 16 + px];
}

// ============ assemble x0 = [cls+pos ; patches+pos] (f64) ============
__global__ void assemble_k(const double* __restrict__ pe, const float* __restrict__ cls,
    const float* __restrict__ pos, double* __restrict__ x0){
    long i = (long)blockIdx.x * 256 + threadIdx.x;
    long total = (long)B_ * NT_ * 768;
    if (i >= total) return;
    int d = (int)(i % 768); long rw = i / 768;
    int n = (int)(rw % NT_); int b = (int)(rw / NT_);
    double v;
    if (n == 0) v = (double)cls[d] + (double)pos[d];
    else        v = pe[((long)b * 196 + (n - 1)) * 768 + d] + (double)pos[(long)n * 768 + d];
    x0[i] = v;
}

__global__ void copy_d(const double* __restrict__ a, double* __restrict__ b, long total){
    long i = (long)blockIdx.x * 256 + threadIdx.x;
    if (i < total) b[i] = a[i];
}

// ============ build sub-branch input (insert 5 prompt tokens after CLS), f64 ============
__global__ void build_sub_k(const double* __restrict__ x0, const float* __restrict__ subp,
    const float* __restrict__ pos, double* __restrict__ xS){
    long i = (long)blockIdx.x * 256 + threadIdx.x;
    long total = (long)B_ * NS_ * 768;
    if (i >= total) return;
    int d = (int)(i % 768); long rw = i / 768;
    int n = (int)(rw % NS_); int b = (int)(rw / NS_);
    double v;
    if (n == 0)      v = x0[((long)b * NT_) * 768 + d];
    else if (n <= 5) v = (double)subp[(n - 1) * 768 + d] + (double)pos[d];
    else             v = x0[((long)b * NT_ + (n - 5)) * 768 + d];
    xS[i] = v;
}

// ============ routing: LN CLS, cosine sim vs keys, argmax (f64) ============
__global__ __launch_bounds__(256) void select_k(
    const double* __restrict__ xA, const float* __restrict__ norm_w,
    const float* __restrict__ norm_b, const float* __restrict__ main_key,
    const float* __restrict__ sub_key, const int* __restrict__ task_id_p,
    int* __restrict__ selm, int* __restrict__ flag)
{
    __shared__ double red[4];
    int b = blockIdx.x, t = threadIdx.x, lane = t & 63, wid = t >> 6;
    const double* xr = xA + (long)b * NT_ * 768;
    double v0 = xr[t], v1 = xr[t + 256], v2 = xr[t + 512];
    double S = block_reduce_sum_d(v0 + v1 + v2, red, lane, wid);
    double m = S * (1.0 / 768.0);
    double d0 = v0 - m, d1 = v1 - m, d2 = v2 - m;
    double Q = block_reduce_sum_d(d0*d0 + d1*d1 + d2*d2, red, lane, wid);
    double rs = 1.0 / sqrt(Q * (1.0 / 768.0) + 1e-6);
    double q0 = d0 * rs * (double)norm_w[t]       + (double)norm_b[t];
    double q1 = d1 * rs * (double)norm_w[t + 256] + (double)norm_b[t + 256];
    double q2 = d2 * rs * (double)norm_w[t + 512] + (double)norm_b[t + 512];
    double qn = block_reduce_sum_d(q0*q0 + q1*q1 + q2*q2, red, lane, wid);
    double qinv = 1.0 / sqrt(fmax(qn, 1e-12));

    int tk = *task_id_p;
    int ncand = tk + 2;
    double best = -1e300; int bsel = 0;
    for (int c = 0; c < ncand; c++){
        const float* cr = (c <= tk) ? (main_key + (long)c * 768) : sub_key;
        double c0 = cr[t], c1 = cr[t + 256], c2 = cr[t + 512];
        double dotq = block_reduce_sum_d(q0*c0 + q1*c1 + q2*c2, red, lane, wid);
        double nc   = block_reduce_sum_d(c0*c0 + c1*c1 + c2*c2, red, lane, wid);
        double sim = dotq * qinv * (1.0 / sqrt(fmax(nc, 1e-12)));
        if (sim > best){ best = sim; bsel = c; }
    }
    if (t == 0){
        int isMain = (bsel <= tk) ? 1 : 0;
        selm[b] = isMain ? bsel : 0;
        flag[b] = isMain;
    }
}

// ============ final head (f64 -> f32 out) ============
__global__ __launch_bounds__(256) void head_k(
    const double* __restrict__ xM, const double* __restrict__ xS,
    const float* __restrict__ norm_w, const float* __restrict__ norm_b,
    const float* __restrict__ fc_w, const float* __restrict__ fc_b,
    const int* __restrict__ flag, float* __restrict__ out)
{
    __shared__ double vec[768];
    __shared__ double red[4];
    int b = blockIdx.x, t = threadIdx.x, lane = t & 63, wid = t >> 6;
    int isMain = flag[b];
    double a0 = 0.0, a1 = 0.0, a2 = 0.0;
    int nrows = isMain ? 1 : 5;
    for (int rI = 0; rI < nrows; rI++){
        const double* xr = isMain ? (xM + (long)b * NT_ * 768)
                                  : (xS + ((long)b * NS_ + 1 + rI) * 768);
        double v0 = xr[t], v1 = xr[t + 256], v2 = xr[t + 512];
        double S = block_reduce_sum_d(v0 + v1 + v2, red, lane, wid);
        double m = S * (1.0 / 768.0);
        double d0 = v0 - m, d1 = v1 - m, d2 = v2 - m;
        double Q = block_reduce_sum_d(d0*d0 + d1*d1 + d2*d2, red, lane, wid);
        double rs = 1.0 / sqrt(Q * (1.0 / 768.0) + 1e-6);
        a0 += d0 * rs * (double)norm_w[t]       + (double)norm_b[t];
        a1 += d1 * rs * (double)norm_w[t + 256] + (double)norm_b[t + 256];
        a2 += d2 * rs * (double)norm_w[t + 512] + (double)norm_b[t + 512];
    }
    double scl = isMain ? 1.0 : 0.2;
    vec[t] = a0 * scl; vec[t + 256] = a1 * scl; vec[t + 512] = a2 * scl;
    __syncthreads();
    if (t < NCLS_){
        const float* wr = fc_w + (long)t * 768;
        double acc = (double)fc_b[t];
#pragma unroll 8
        for (int j = 0; j < 768; j++) acc += vec[j] * (double)wr[j];
        out[b * NCLS_ + t] = (float)acc;
    }
}

// ================= host-side block runner =================
struct Params {
    const float *qkv_w, *qkv_b, *proj_w, *proj_b;
    const float *ln1_w, *ln1_b, *ln2_w, *ln2_b;
    const float *fc1_w, *fc1_b, *fc2_w, *fc2_b;
    const float *prompts; const int* selm;
    double *lnb, *qkvb, *attb, *hidb, *avn;
};

static void run_block_h(hipStream_t stream, double* x, int Ntok, int layer,
                        bool deep, int li, const Params& P)
{
    int M = B_ * Ntok;
    int gy = (M + 63) / 64;
    ln_k<<<M, 256, 0, stream>>>(x, P.ln1_w + layer * 768, P.ln1_b + layer * 768, P.lnb);
    gemm_dd<0><<<dim3(2304 / 64, gy), 256, 0, stream>>>(P.lnb,
        P.qkv_w + (long)layer * 2304 * 768, P.qkv_b + layer * 2304, nullptr,
        P.qkvb, M, 768, 2304);
    if (!deep){
        attn_std_d2<<<dim3(B_ * HEADS_, Ntok), 256, 0, stream>>>(P.qkvb, P.attb, Ntok);
    } else {
        attn_deep_d2<<<dim3(B_, NT_), 256, 0, stream>>>(P.qkvb, P.prompts, P.selm, P.avn, li);
        long tot = (long)B_ * NT_ * 768;
        scramble_k<<<(int)((tot + 255) / 256), 256, 0, stream>>>(P.avn, P.attb);
    }
    gemm_dd<2><<<dim3(768 / 64, gy), 256, 0, stream>>>(P.attb,
        P.proj_w + (long)layer * 768 * 768, P.proj_b + layer * 768, x, x, M, 768, 768);
    ln_k<<<M, 256, 0, stream>>>(x, P.ln2_w + layer * 768, P.ln2_b + layer * 768, P.lnb);
    gemm_dd<1><<<dim3(3072 / 64, gy), 256, 0, stream>>>(P.lnb,
        P.fc1_w + (long)layer * 3072 * 768, P.fc1_b + layer * 3072, nullptr,
        P.hidb, M, 768, 3072);
    gemm_dd<2><<<dim3(768 / 64, gy), 256, 0, stream>>>(P.hidb,
        P.fc2_w + (long)layer * 768 * 3072, P.fc2_b + layer * 768, x, x, M, 3072, 768);
}

extern "C" void kernel_launch(void* const* d_in, const int* in_sizes, int n_in,
                              void* d_out, int out_size, void* d_ws, size_t ws_size,
                              hipStream_t stream)
{
    (void)in_sizes; (void)n_in; (void)out_size; (void)ws_size;
    const float* inputs   = (const float*)d_in[0];
    const int*   task_id  = (const int*)  d_in[1];
    const float* patch_w  = (const float*)d_in[2];
    const float* patch_b  = (const float*)d_in[3];
    const float* cls_tok  = (const float*)d_in[4];
    const float* pos      = (const float*)d_in[5];
    const float* qkv_w    = (const float*)d_in[6];
    const float* qkv_b    = (const float*)d_in[7];
    const float* proj_w   = (const float*)d_in[8];
    const float* proj_b   = (const float*)d_in[9];
    const float* ln1_w    = (const float*)d_in[10];
    const float* ln1_b    = (const float*)d_in[11];
    const float* ln2_w    = (const float*)d_in[12];
    const float* ln2_b    = (const float*)d_in[13];
    const float* fc1_w    = (const float*)d_in[14];
    const float* fc1_b    = (const float*)d_in[15];
    const float* fc2_w    = (const float*)d_in[16];
    const float* fc2_b    = (const float*)d_in[17];
    const float* norm_w   = (const float*)d_in[18];
    const float* norm_b   = (const float*)d_in[19];
    const float* fc_w     = (const float*)d_in[20];
    const float* fc_b     = (const float*)d_in[21];
    const float* main_key = (const float*)d_in[22];
    const float* sub_key  = (const float*)d_in[23];
    const float* m_prompts= (const float*)d_in[24];
    const float* s_prompt = (const float*)d_in[25];
    float* out = (float*)d_out;

    char* wsb = (char*)d_ws;
    size_t off = 0;
    auto alloc = [&](long ndbl) -> double* {
        double* p = (double*)(wsb + off);
        off += ((size_t)ndbl * 8 + 255) & ~(size_t)255;
        return p;
    };
    double* x0   = alloc((long)B_ * NT_ * 768);
    double* xP   = alloc((long)B_ * NT_ * 768);
    double* xS   = alloc((long)B_ * NS_ * 768);
    double* lnb  = alloc((long)B_ * NS_ * 768);
    double* attb = alloc((long)B_ * NS_ * 768);
    double* big  = alloc((long)B_ * NS_ * 3072);   // shared qkv / mlp-hidden
    int*   selm  = (int*)alloc(8);
    int*   flag  = (int*)alloc(8);
    // avn aliases big's tail: qkv (deep layers, main branch) uses B*NT*2304 of big;
    // avn needs B*NT*768 and big has B*NS*3072 total -> disjoint. fc1 overwrites later (avn dead).
    double* avn  = big + (long)B_ * NT_ * 2304;

    Params P;
    P.qkv_w = qkv_w; P.qkv_b = qkv_b; P.proj_w = proj_w; P.proj_b = proj_b;
    P.ln1_w = ln1_w; P.ln1_b = ln1_b; P.ln2_w = ln2_w; P.ln2_b = ln2_b;
    P.fc1_w = fc1_w; P.fc1_b = fc1_b; P.fc2_w = fc2_w; P.fc2_b = fc2_b;
    P.prompts = m_prompts; P.selm = selm;
    P.lnb = lnb; P.qkvb = big; P.attb = attb; P.hidb = big; P.avn = avn;

    const long XN = (long)B_ * NT_ * 768;

    // -------- patch embed --------
    {
        long tot = (long)B_ * 196 * 768;
        double* un  = big;
        double* peo = big + (long)B_ * NS_ * 1536;
        unfold_k<<<(int)((tot + 255) / 256), 256, 0, stream>>>(inputs, un);
        gemm_dd<0><<<dim3(768 / 64, (3136 + 63) / 64), 256, 0, stream>>>(
            un, patch_w, patch_b, nullptr, peo, 3136, 768, 768);
        assemble_k<<<(int)((XN + 255) / 256), 256, 0, stream>>>(peo, cls_tok, pos, x0);
        copy_d<<<(int)((XN + 255) / 256), 256, 0, stream>>>(x0, xP, XN);
    }

    // -------- pass A (query) --------
    for (int i = 0; i < DEPTH_; i++)
        run_block_h(stream, xP, NT_, i, false, 0, P);

    // -------- routing --------
    select_k<<<16, 256, 0, stream>>>(xP, norm_w, norm_b, main_key, sub_key,
                                     task_id, selm, flag);

    // -------- main branch (full recompute from x0) --------
    copy_d<<<(int)((XN + 255) / 256), 256, 0, stream>>>(x0, xP, XN);
    for (int i = 0; i < DEPTH_; i++){
        bool deep = (i >= 2 && i <= 4);
        run_block_h(stream, xP, NT_, i, deep, i - 2, P);
    }

    // -------- sub branch --------
    {
        long tot = (long)B_ * NS_ * 768;
        build_sub_k<<<(int)((tot + 255) / 256), 256, 0, stream>>>(x0, s_prompt, pos, xS);
    }
    for (int i = 0; i < DEPTH_; i++)
        run_block_h(stream, xS, NS_, i, false, 0, P);

    // -------- heads + per-sample select --------
    head_k<<<16, 256, 0, stream>>>(xP, xS, norm_w, norm_b, fc_w, fc_b, flag, out);
}

// Round 6
// 17575.500 us; speedup vs baseline: 5.1338x; 5.1338x over previous
//
#include <hip/hip_runtime.h>
#include <math.h>

// ---------------- constants ----------------
#define B_    16
#define NT_   197
#define NS_   202
#define HEADS_ 12
#define DEPTH_ 12
#define NCLS_ 100
#define MROW_ (B_ * NT_)   // 3152  (pass A / main rows)
#define SROW_ (B_ * NS_)   // 3232  (sub rows)
#define CROW_ (MROW_ + SROW_) // 6384 (concat rows)

typedef __attribute__((ext_vector_type(8))) short short8v;
typedef __attribute__((ext_vector_type(4))) float f32x4;

// f32 -> bf16 bits (RNE)
__device__ __forceinline__ short f2bf(float f){
    unsigned u = __builtin_bit_cast(unsigned, f);
    unsigned r = (u + 0x7FFFu + ((u >> 16) & 1u)) >> 16;
    return (short)r;
}
__device__ __forceinline__ float bf2f(short s){
    unsigned u = ((unsigned)(unsigned short)s) << 16;
    return __builtin_bit_cast(float, u);
}

// ============ float block reduce (256 thr) ============
__device__ __forceinline__ float block_reduce_sum_f(float s, float* red, int lane, int wid){
#pragma unroll
    for (int off = 32; off; off >>= 1) s += __shfl_xor(s, off);
    if (lane == 0) red[wid] = s;
    __syncthreads();
    float S = red[0] + red[1] + red[2] + red[3];
    __syncthreads();
    return S;
}
// ============ double block reduce (256 thr) — routing/head only ============
__device__ __forceinline__ double block_reduce_sum_d(double s, double* red, int lane, int wid){
#pragma unroll
    for (int off = 32; off; off >>= 1) s += __shfl_xor(s, off);
    if (lane == 0) red[wid] = s;
    __syncthreads();
    double S = red[0] + red[1] + red[2] + red[3];
    __syncthreads();
    return S;
}

// ============ bf16 MFMA GEMM: C = A @ W^T + bias (+epilogue) ============
// A: M x K bf16 row-major. W: N x K f32 row-major (cast to bf16 in staging).
// EPI 0: Cf f32. EPI 1: exact GELU -> Cb bf16. EPI 2: Cf = Res + .. (f32).
// Tile 128x128, BK=32, 4 waves (2x2 of 64x64), mfma_f32_16x16x32_bf16.
// K % 32 == 0, N % 128 == 0, M guarded.
template<int EPI>
__global__ __launch_bounds__(256) void gemm_bf16(
    const short* __restrict__ A, const float* __restrict__ W,
    const float* __restrict__ bias, const float* __restrict__ Res,
    float* __restrict__ Cf, short* __restrict__ Cb, int M, int K, int N)
{
    __shared__ short As[128 * 48];   // 32 k + 16 pad per row (96B stride, 16B-aligned)
    __shared__ short Bs[128 * 48];
    const int t = threadIdx.x;
    const int lane = t & 63, wid = t >> 6;
    const int wr = wid >> 1, wc = wid & 1;           // wave 2x2 over 64x64 subtiles
    const long row0 = (long)blockIdx.y * 128;
    const long col0 = (long)blockIdx.x * 128;

    f32x4 acc[4][4];
#pragma unroll
    for (int i = 0; i < 4; i++)
#pragma unroll
        for (int j = 0; j < 4; j++) acc[i][j] = (f32x4){0.f, 0.f, 0.f, 0.f};

    const int l15 = lane & 15, lkg = lane >> 4;      // fragment row / k-group
    const int ar = t >> 2, ac = t & 3;               // A staging: row, 8-elem chunk
    const int bn = t >> 1, bh = t & 1;               // B staging: col row, 16-elem half

    for (int k0 = 0; k0 < K; k0 += 32){
        // ---- stage A (128x32 bf16) : 2 iters of 64 rows ----
#pragma unroll
        for (int it = 0; it < 2; it++){
            int r = ar + it * 64;
            long gr = row0 + r;
            uint4 v = {0u, 0u, 0u, 0u};
            if (gr < M) v = *(const uint4*)(A + gr * K + k0 + ac * 8);
            *(uint4*)(&As[r * 48 + ac * 8]) = v;
        }
        // ---- stage B (128 cols x 32 k, f32 -> bf16) ----
        {
            const float* Wp = W + (col0 + bn) * K + k0 + bh * 16;
            unsigned rr[8];
#pragma unroll
            for (int g = 0; g < 8; g++){
                float2 f = *(const float2*)(Wp + g * 2);
                rr[g] = ((unsigned)(unsigned short)f2bf(f.x)) |
                        (((unsigned)(unsigned short)f2bf(f.y)) << 16);
            }
            uint4 lo = {rr[0], rr[1], rr[2], rr[3]};
            uint4 hi = {rr[4], rr[5], rr[6], rr[7]};
            *(uint4*)(&Bs[bn * 48 + bh * 16])     = lo;
            *(uint4*)(&Bs[bn * 48 + bh * 16 + 8]) = hi;
        }
        __syncthreads();

        // ---- fragments + 16 MFMA ----
        short8v a[4], b[4];
#pragma unroll
        for (int i = 0; i < 4; i++)
            a[i] = *(const short8v*)(&As[(wr * 64 + i * 16 + l15) * 48 + lkg * 8]);
#pragma unroll
        for (int j = 0; j < 4; j++)
            b[j] = *(const short8v*)(&Bs[(wc * 64 + j * 16 + l15) * 48 + lkg * 8]);
#pragma unroll
        for (int i = 0; i < 4; i++)
#pragma unroll
            for (int j = 0; j < 4; j++)
                acc[i][j] = __builtin_amdgcn_mfma_f32_16x16x32_bf16(a[i], b[j], acc[i][j], 0, 0, 0);
        __syncthreads();
    }

    // ---- epilogue: C row=(lane>>4)*4+q, col=lane&15 (m89/m91-verified) ----
#pragma unroll
    for (int i = 0; i < 4; i++){
#pragma unroll
        for (int q = 0; q < 4; q++){
            long gr = row0 + wr * 64 + i * 16 + lkg * 4 + q;
            if (gr >= M) continue;
#pragma unroll
            for (int j = 0; j < 4; j++){
                long gc = col0 + wc * 64 + j * 16 + l15;
                float v = acc[i][j][q] + bias[gc];
                if (EPI == 1){
                    v = 0.5f * v * (1.f + erff(v * 0.70710678118654752f));
                    Cb[gr * N + gc] = f2bf(v);
                } else if (EPI == 2){
                    Cf[gr * N + gc] = v + Res[gr * N + gc];
                } else {
                    Cf[gr * N + gc] = v;
                }
            }
        }
    }
}

// ============ LayerNorm (two-pass f32) : x f32 -> lnb bf16 ============
__global__ __launch_bounds__(256) void ln_k(const float* __restrict__ x,
    const float* __restrict__ w, const float* __restrict__ b,
    short* __restrict__ y)
{
    __shared__ float red[4];
    int row = blockIdx.x, t = threadIdx.x;
    int lane = t & 63, wid = t >> 6;
    const float* xr = x + (long)row * 768;
    float v0 = xr[t], v1 = xr[t + 256], v2 = xr[t + 512];
    float S = block_reduce_sum_f(v0 + v1 + v2, red, lane, wid);
    float m = S * (1.f / 768.f);
    float d0 = v0 - m, d1 = v1 - m, d2 = v2 - m;
    float Q = block_reduce_sum_f(d0*d0 + d1*d1 + d2*d2, red, lane, wid);
    float rs = 1.f / sqrtf(Q * (1.f / 768.f) + 1e-6f);
    short* yr = y + (long)row * 768;
    yr[t]       = f2bf(d0 * rs * w[t]       + b[t]);
    yr[t + 256] = f2bf(d1 * rs * w[t + 256] + b[t + 256]);
    yr[t + 512] = f2bf(d2 * rs * w[t + 512] + b[t + 512]);
}

// ============ std MHA (f32, dumb-correct structure from round 5) ============
// qkv: rows (b*Ntok+n) x 2304 f32; o: bf16 rows x 768
__global__ __launch_bounds__(256) void attn_std_k(
    const float* __restrict__ qkv, short* __restrict__ o, int Ntok)
{
    __shared__ float q[64];
    __shared__ float p[256];
    __shared__ float red[256];
    int bh = blockIdx.x;
    int b = bh / HEADS_, h = bh % HEADS_;
    int n = blockIdx.y, t = threadIdx.x;
    const long rb = (long)b * Ntok;

    if (t < 64) q[t] = qkv[(rb + n) * 2304 + h * 64 + t] * 0.125f;
    __syncthreads();

    float s = -1e30f;
    if (t < Ntok){
        const float* kr = qkv + (rb + t) * 2304 + 768 + h * 64;
        float a = 0.f;
#pragma unroll 8
        for (int j = 0; j < 64; j++) a += q[j] * kr[j];
        s = a;
    }
    red[t] = s; __syncthreads();
    for (int w = 128; w; w >>= 1){ if (t < w) red[t] = fmaxf(red[t], red[t+w]); __syncthreads(); }
    float mx = red[0]; __syncthreads();
    float e = (t < Ntok) ? expf(s - mx) : 0.f;
    red[t] = e; __syncthreads();
    for (int w = 128; w; w >>= 1){ if (t < w) red[t] += red[t+w]; __syncthreads(); }
    float inv = 1.f / red[0];
    p[t] = e * inv;
    __syncthreads();

    if (t < 64){
        float a = 0.f;
        for (int m = 0; m < Ntok; m++)
            a += p[m] * qkv[(rb + m) * 2304 + 1536 + h * 64 + t];
        o[(rb + n) * 768 + h * 64 + t] = f2bf(a);
    }
}

// ============ deep attention (768-dim head + 5 prompt K/V), f32 ============
__global__ __launch_bounds__(256) void attn_deep_k(
    const float* __restrict__ qkv, const float* __restrict__ prompts,
    const int* __restrict__ selm, float* __restrict__ avn, int li)
{
    __shared__ float q[768];
    __shared__ float p[256];
    __shared__ float red[256];
    int b = blockIdx.x, n = blockIdx.y, t = threadIdx.x;

    const float* qr = qkv + (long)(b * NT_ + n) * 2304;
    q[t] = qr[t]; q[t + 256] = qr[t + 256]; q[t + 512] = qr[t + 512];
    __syncthreads();

    const float* kp = prompts + ((long)selm[b] * 6 + 2 * li) * 5 * 768;
    const float* vp = kp + 5 * 768;

    float s = -1e30f;
    if (t < 202){
        float a = 0.f;
        if (t < 5){
            const float* kr = kp + t * 768;
#pragma unroll 8
            for (int j = 0; j < 768; j++) a += q[j] * kr[j];
        } else {
            const float* kr = qkv + (long)(b * NT_ + (t - 5)) * 2304 + 768;
#pragma unroll 8
            for (int j = 0; j < 768; j++) a += q[j] * kr[j];
        }
        s = a * 0.125f;
    }
    red[t] = s; __syncthreads();
    for (int w = 128; w; w >>= 1){ if (t < w) red[t] = fmaxf(red[t], red[t+w]); __syncthreads(); }
    float mx = red[0]; __syncthreads();
    float e = (t < 202) ? expf(s - mx) : 0.f;
    red[t] = e; __syncthreads();
    for (int w = 128; w; w >>= 1){ if (t < w) red[t] += red[t+w]; __syncthreads(); }
    float inv = 1.f / red[0];
    p[t] = e * inv;
    __syncthreads();

    float a0 = 0.f, a1 = 0.f, a2 = 0.f;
    for (int m = 0; m < 5; m++){
        const float* vr = vp + m * 768;
        float pm = p[m];
        a0 += pm * vr[t]; a1 += pm * vr[t + 256]; a2 += pm * vr[t + 512];
    }
    for (int m = 5; m < 202; m++){
        const float* vr = qkv + (long)(b * NT_ + (m - 5)) * 2304 + 1536;
        float pm = p[m];
        a0 += pm * vr[t]; a1 += pm * vr[t + 256]; a2 += pm * vr[t + 512];
    }
    float* orow = avn + (long)(b * NT_ + n) * 768;
    orow[t] = a0; orow[t + 256] = a1; orow[t + 512] = a2;
}

// ============ scramble: out[b][f] = avn[b][f%197][f/197], f = n'*768+d' ============
__global__ void scramble_k(const float* __restrict__ avn, short* __restrict__ o){
    long i = (long)blockIdx.x * 256 + threadIdx.x;
    const long per = (long)NT_ * 768;
    long total = (long)B_ * per;
    if (i >= total) return;
    int b = (int)(i / per);
    long f = i - (long)b * per;
    int n = (int)(f % NT_);
    int d = (int)(f / NT_);
    o[i] = f2bf(avn[(long)b * per + (long)n * 768 + d]);
}

// ============ patch unfold (f32 -> bf16) ============
__global__ void unfold_k(const float* __restrict__ in, short* __restrict__ out){
    long i = (long)blockIdx.x * 256 + threadIdx.x;
    long total = (long)B_ * 196 * 768;
    if (i >= total) return;
    int f = (int)(i % 768); long rw = i / 768;
    int t = (int)(rw % 196); int b = (int)(rw / 196);
    int gy = t / 14, gx = t % 14;
    int c = f >> 8, rem = f & 255, py = rem >> 4, px = rem & 15;
    out[i] = f2bf(in[(((long)(b * 3 + c) * 224) + gy * 16 + py) * 224 + gx * 16 + px]);
}

// ============ assemble x0 = [cls+pos ; patches+pos] (f32) ============
__global__ void assemble_k(const float* __restrict__ pe, const float* __restrict__ cls,
    const float* __restrict__ pos, float* __restrict__ x0){
    long i = (long)blockIdx.x * 256 + threadIdx.x;
    long total = (long)B_ * NT_ * 768;
    if (i >= total) return;
    int d = (int)(i % 768); long rw = i / 768;
    int n = (int)(rw % NT_); int b = (int)(rw / NT_);
    float v;
    if (n == 0) v = cls[d] + pos[d];
    else        v = pe[((long)b * 196 + (n - 1)) * 768 + d] + pos[(long)n * 768 + d];
    x0[i] = v;
}

__global__ void copy_f(const float* __restrict__ a, float* __restrict__ b, long total){
    long i = (long)blockIdx.x * 256 + threadIdx.x;
    if (i < total) b[i] = a[i];
}

// ============ build sub-branch rows (insert 5 prompt tokens after CLS) ============
__global__ void build_sub_k(const float* __restrict__ x0, const float* __restrict__ subp,
    const float* __restrict__ pos, float* __restrict__ xSub){
    long i = (long)blockIdx.x * 256 + threadIdx.x;
    long total = (long)B_ * NS_ * 768;
    if (i >= total) return;
    int d = (int)(i % 768); long rw = i / 768;
    int n = (int)(rw % NS_); int b = (int)(rw / NS_);
    float v;
    if (n == 0)      v = x0[((long)b * NT_) * 768 + d];
    else if (n <= 5) v = subp[(n - 1) * 768 + d] + pos[d];
    else             v = x0[((long)b * NT_ + (n - 5)) * 768 + d];
    xSub[i] = v;
}

// ============ routing (f64 internals, f32 data) ============
__global__ __launch_bounds__(256) void select_k(
    const float* __restrict__ xA, const float* __restrict__ norm_w,
    const float* __restrict__ norm_b, const float* __restrict__ main_key,
    const float* __restrict__ sub_key, const int* __restrict__ task_id_p,
    int* __restrict__ selm, int* __restrict__ flag)
{
    __shared__ double red[4];
    int b = blockIdx.x, t = threadIdx.x, lane = t & 63, wid = t >> 6;
    const float* xr = xA + (long)b * NT_ * 768;
    double v0 = xr[t], v1 = xr[t + 256], v2 = xr[t + 512];
    double S = block_reduce_sum_d(v0 + v1 + v2, red, lane, wid);
    double m = S * (1.0 / 768.0);
    double d0 = v0 - m, d1 = v1 - m, d2 = v2 - m;
    double Q = block_reduce_sum_d(d0*d0 + d1*d1 + d2*d2, red, lane, wid);
    double rs = 1.0 / sqrt(Q * (1.0 / 768.0) + 1e-6);
    double q0 = d0 * rs * (double)norm_w[t]       + (double)norm_b[t];
    double q1 = d1 * rs * (double)norm_w[t + 256] + (double)norm_b[t + 256];
    double q2 = d2 * rs * (double)norm_w[t + 512] + (double)norm_b[t + 512];
    double qn = block_reduce_sum_d(q0*q0 + q1*q1 + q2*q2, red, lane, wid);
    double qinv = 1.0 / sqrt(fmax(qn, 1e-12));

    int tk = *task_id_p;
    int ncand = tk + 2;
    double best = -1e300; int bsel = 0;
    for (int c = 0; c < ncand; c++){
        const float* cr = (c <= tk) ? (main_key + (long)c * 768) : sub_key;
        double c0 = cr[t], c1 = cr[t + 256], c2 = cr[t + 512];
        double dotq = block_reduce_sum_d(q0*c0 + q1*c1 + q2*c2, red, lane, wid);
        double nc   = block_reduce_sum_d(c0*c0 + c1*c1 + c2*c2, red, lane, wid);
        double sim = dotq * qinv * (1.0 / sqrt(fmax(nc, 1e-12)));
        if (sim > best){ best = sim; bsel = c; }
    }
    if (t == 0){
        int isMain = (bsel <= tk) ? 1 : 0;
        selm[b] = isMain ? bsel : 0;
        flag[b] = isMain;
    }
}

// ============ final head (f64 internals, f32 data, f32 out) ============
__global__ __launch_bounds__(256) void head_k(
    const float* __restrict__ xM, const float* __restrict__ xSub,
    const float* __restrict__ norm_w, const float* __restrict__ norm_b,
    const float* __restrict__ fc_w, const float* __restrict__ fc_b,
    const int* __restrict__ flag, float* __restrict__ out)
{
    __shared__ double vec[768];
    __shared__ double red[4];
    int b = blockIdx.x, t = threadIdx.x, lane = t & 63, wid = t >> 6;
    int isMain = flag[b];
    double a0 = 0.0, a1 = 0.0, a2 = 0.0;
    int nrows = isMain ? 1 : 5;
    for (int rI = 0; rI < nrows; rI++){
        const float* xr = isMain ? (xM + (long)b * NT_ * 768)
                                 : (xSub + ((long)b * NS_ + 1 + rI) * 768);
        double v0 = xr[t], v1 = xr[t + 256], v2 = xr[t + 512];
        double S = block_reduce_sum_d(v0 + v1 + v2, red, lane, wid);
        double m = S * (1.0 / 768.0);
        double d0 = v0 - m, d1 = v1 - m, d2 = v2 - m;
        double Q = block_reduce_sum_d(d0*d0 + d1*d1 + d2*d2, red, lane, wid);
        double rs = 1.0 / sqrt(Q * (1.0 / 768.0) + 1e-6);
        a0 += d0 * rs * (double)norm_w[t]       + (double)norm_b[t];
        a1 += d1 * rs * (double)norm_w[t + 256] + (double)norm_b[t + 256];
        a2 += d2 * rs * (double)norm_w[t + 512] + (double)norm_b[t + 512];
    }
    double scl = isMain ? 1.0 : 0.2;
    vec[t] = a0 * scl; vec[t + 256] = a1 * scl; vec[t + 512] = a2 * scl;
    __syncthreads();
    if (t < NCLS_){
        const float* wr = fc_w + (long)t * 768;
        double acc = (double)fc_b[t];
#pragma unroll 8
        for (int j = 0; j < 768; j++) acc += vec[j] * (double)wr[j];
        out[b * NCLS_ + t] = (float)acc;
    }
}

// ================= host-side =================
struct Params {
    const float *qkv_w, *qkv_b, *proj_w, *proj_b;
    const float *ln1_w, *ln1_b, *ln2_w, *ln2_b;
    const float *fc1_w, *fc1_b, *fc2_w, *fc2_b;
    const float *prompts; const int* selm;
    short *lnb, *attb, *hidb;
    float *qkvb, *avn;
};

// mode 0: concat (std attn on both segments)  mode 1: main std  mode 2: main deep
static void run_layer(hipStream_t st, float* x, int M, int layer, int mode, int li,
                      const Params& P)
{
    int gy = (M + 127) / 128;
    ln_k<<<M, 256, 0, st>>>(x, P.ln1_w + layer * 768, P.ln1_b + layer * 768, P.lnb);
    gemm_bf16<0><<<dim3(2304 / 128, gy), 256, 0, st>>>(P.lnb,
        P.qkv_w + (long)layer * 2304 * 768, P.qkv_b + layer * 2304, nullptr,
        P.qkvb, nullptr, M, 768, 2304);
    if (mode == 0){
        attn_std_k<<<dim3(B_ * HEADS_, NT_), 256, 0, st>>>(P.qkvb, P.attb, NT_);
        attn_std_k<<<dim3(B_ * HEADS_, NS_), 256, 0, st>>>(
            P.qkvb + (long)MROW_ * 2304, P.attb + (long)MROW_ * 768, NS_);
    } else if (mode == 1){
        attn_std_k<<<dim3(B_ * HEADS_, NT_), 256, 0, st>>>(P.qkvb, P.attb, NT_);
    } else {
        attn_deep_k<<<dim3(B_, NT_), 256, 0, st>>>(P.qkvb, P.prompts, P.selm, P.avn, li);
        long tot = (long)MROW_ * 768;
        scramble_k<<<(int)((tot + 255) / 256), 256, 0, st>>>(P.avn, P.attb);
    }
    gemm_bf16<2><<<dim3(768 / 128, gy), 256, 0, st>>>(P.attb,
        P.proj_w + (long)layer * 768 * 768, P.proj_b + layer * 768, x,
        x, nullptr, M, 768, 768);
    ln_k<<<M, 256, 0, st>>>(x, P.ln2_w + layer * 768, P.ln2_b + layer * 768, P.lnb);
    gemm_bf16<1><<<dim3(3072 / 128, gy), 256, 0, st>>>(P.lnb,
        P.fc1_w + (long)layer * 3072 * 768, P.fc1_b + layer * 3072, nullptr,
        nullptr, P.hidb, M, 768, 3072);
    gemm_bf16<2><<<dim3(768 / 128, gy), 256, 0, st>>>(P.hidb,
        P.fc2_w + (long)layer * 768 * 3072, P.fc2_b + layer * 768, x,
        x, nullptr, M, 3072, 768);
}

extern "C" void kernel_launch(void* const* d_in, const int* in_sizes, int n_in,
                              void* d_out, int out_size, void* d_ws, size_t ws_size,
                              hipStream_t stream)
{
    (void)in_sizes; (void)n_in; (void)out_size; (void)ws_size;
    const float* inputs   = (const float*)d_in[0];
    const int*   task_id  = (const int*)  d_in[1];
    const float* patch_w  = (const float*)d_in[2];
    const float* patch_b  = (const float*)d_in[3];
    const float* cls_tok  = (const float*)d_in[4];
    const float* pos      = (const float*)d_in[5];
    const float* qkv_w    = (const float*)d_in[6];
    const float* qkv_b    = (const float*)d_in[7];
    const float* proj_w   = (const float*)d_in[8];
    const float* proj_b   = (const float*)d_in[9];
    const float* ln1_w    = (const float*)d_in[10];
    const float* ln1_b    = (const float*)d_in[11];
    const float* ln2_w    = (const float*)d_in[12];
    const float* ln2_b    = (const float*)d_in[13];
    const float* fc1_w    = (const float*)d_in[14];
    const float* fc1_b    = (const float*)d_in[15];
    const float* fc2_w    = (const float*)d_in[16];
    const float* fc2_b    = (const float*)d_in[17];
    const float* norm_w   = (const float*)d_in[18];
    const float* norm_b   = (const float*)d_in[19];
    const float* fc_w     = (const float*)d_in[20];
    const float* fc_b     = (const float*)d_in[21];
    const float* main_key = (const float*)d_in[22];
    const float* sub_key  = (const float*)d_in[23];
    const float* m_prompts= (const float*)d_in[24];
    const float* s_prompt = (const float*)d_in[25];
    float* out = (float*)d_out;

    char* wsb = (char*)d_ws;
    size_t off = 0;
    auto allocB = [&](size_t bytes) -> void* {
        void* p = (void*)(wsb + off);
        off += (bytes + 255) & ~(size_t)255;
        return p;
    };
    float* x0   = (float*)allocB((size_t)MROW_ * 768 * 4);
    float* xC   = (float*)allocB((size_t)CROW_ * 768 * 4);   // concat: passA rows | sub rows
    float* xM   = (float*)allocB((size_t)MROW_ * 768 * 4);   // main branch state
    short* lnb  = (short*)allocB((size_t)CROW_ * 768 * 2);
    short* attb = (short*)allocB((size_t)CROW_ * 768 * 2);
    float* qkvb = (float*)allocB((size_t)CROW_ * 2304 * 4);
    short* hidb = (short*)allocB((size_t)CROW_ * 3072 * 2);
    float* avn  = (float*)allocB((size_t)MROW_ * 768 * 4);
    int*   selm = (int*)allocB(64);
    int*   flag = (int*)allocB(64);

    Params P;
    P.qkv_w = qkv_w; P.qkv_b = qkv_b; P.proj_w = proj_w; P.proj_b = proj_b;
    P.ln1_w = ln1_w; P.ln1_b = ln1_b; P.ln2_w = ln2_w; P.ln2_b = ln2_b;
    P.fc1_w = fc1_w; P.fc1_b = fc1_b; P.fc2_w = fc2_w; P.fc2_b = fc2_b;
    P.prompts = m_prompts; P.selm = selm;
    P.lnb = lnb; P.attb = attb; P.hidb = hidb; P.qkvb = qkvb; P.avn = avn;

    const long XN = (long)MROW_ * 768;

    // -------- patch embed --------
    {
        long tot = (long)B_ * 196 * 768;
        short* un  = hidb;            // embed-phase scratch (dead before layer loop)
        float* peo = qkvb;
        unfold_k<<<(int)((tot + 255) / 256), 256, 0, stream>>>(inputs, un);
        gemm_bf16<0><<<dim3(768 / 128, (3136 + 127) / 128), 256, 0, stream>>>(
            un, patch_w, patch_b, nullptr, peo, nullptr, 3136, 768, 768);
        assemble_k<<<(int)((XN + 255) / 256), 256, 0, stream>>>(peo, cls_tok, pos, x0);
        copy_f<<<(int)((XN + 255) / 256), 256, 0, stream>>>(x0, xC, XN);
        long st = (long)SROW_ * 768;
        build_sub_k<<<(int)((st + 255) / 256), 256, 0, stream>>>(x0, s_prompt, pos,
                                                                 xC + (long)MROW_ * 768);
    }

    // -------- concatenated pass A + sub branch (12 shared-weight std layers) --------
    for (int i = 0; i < DEPTH_; i++){
        run_layer(stream, xC, CROW_, i, 0, 0, P);
        if (i == 1)  // snapshot pass-A state == main-branch state after layers 0-1
            copy_f<<<(int)((XN + 255) / 256), 256, 0, stream>>>(xC, xM, XN);
    }

    // -------- routing (uses pass-A final CLS) --------
    select_k<<<16, 256, 0, stream>>>(xC, norm_w, norm_b, main_key, sub_key,
                                     task_id, selm, flag);

    // -------- main branch layers 2..11 (deep prompts at 2,3,4) --------
    for (int i = 2; i < DEPTH_; i++){
        int mode = (i >= 2 && i <= 4) ? 2 : 1;
        run_layer(stream, xM, MROW_, i, mode, i - 2, P);
    }

    // -------- heads + per-sample select --------
    head_k<<<16, 256, 0, stream>>>(xM, xC + (long)MROW_ * 768, norm_w, norm_b,
                                   fc_w, fc_b, flag, out);
}

// Round 7
// 11871.738 us; speedup vs baseline: 7.6003x; 1.4804x over previous
//
#include <hip/hip_runtime.h>
#include <math.h>

// ---------------- constants ----------------
#define B_    16
#define NT_   197
#define NS_   202
#define HEADS_ 12
#define DEPTH_ 12
#define NCLS_ 100
#define MROW_ (B_ * NT_)      // 3152
#define SROW_ (B_ * NS_)      // 3232
#define CROW_ (MROW_ + SROW_) // 6384

typedef __attribute__((ext_vector_type(8))) short short8v;
typedef __attribute__((ext_vector_type(4))) float f32x4;

// f32 -> bf16 bits (RNE)
__device__ __forceinline__ short f2bf(float f){
    unsigned u = __builtin_bit_cast(unsigned, f);
    unsigned r = (u + 0x7FFFu + ((u >> 16) & 1u)) >> 16;
    return (short)r;
}

// ============ float block reduce (256 thr) ============
__device__ __forceinline__ float block_reduce_sum_f(float s, float* red, int lane, int wid){
#pragma unroll
    for (int off = 32; off; off >>= 1) s += __shfl_xor(s, off);
    if (lane == 0) red[wid] = s;
    __syncthreads();
    float S = red[0] + red[1] + red[2] + red[3];
    __syncthreads();
    return S;
}
// ============ double block reduce (256 thr) — routing/head only ============
__device__ __forceinline__ double block_reduce_sum_d(double s, double* red, int lane, int wid){
#pragma unroll
    for (int off = 32; off; off >>= 1) s += __shfl_xor(s, off);
    if (lane == 0) red[wid] = s;
    __syncthreads();
    double S = red[0] + red[1] + red[2] + red[3];
    __syncthreads();
    return S;
}

// ============ bf16 MFMA GEMM: C = A @ W^T + bias (+epilogue) ============
// (unchanged from round 6 — verified green)
template<int EPI>
__global__ __launch_bounds__(256) void gemm_bf16(
    const short* __restrict__ A, const float* __restrict__ W,
    const float* __restrict__ bias, const float* __restrict__ Res,
    float* __restrict__ Cf, short* __restrict__ Cb, int M, int K, int N)
{
    __shared__ short As[128 * 48];
    __shared__ short Bs[128 * 48];
    const int t = threadIdx.x;
    const int lane = t & 63, wid = t >> 6;
    const int wr = wid >> 1, wc = wid & 1;
    const long row0 = (long)blockIdx.y * 128;
    const long col0 = (long)blockIdx.x * 128;

    f32x4 acc[4][4];
#pragma unroll
    for (int i = 0; i < 4; i++)
#pragma unroll
        for (int j = 0; j < 4; j++) acc[i][j] = (f32x4){0.f, 0.f, 0.f, 0.f};

    const int l15 = lane & 15, lkg = lane >> 4;
    const int ar = t >> 2, ac = t & 3;
    const int bn = t >> 1, bh = t & 1;

    for (int k0 = 0; k0 < K; k0 += 32){
#pragma unroll
        for (int it = 0; it < 2; it++){
            int r = ar + it * 64;
            long gr = row0 + r;
            uint4 v = {0u, 0u, 0u, 0u};
            if (gr < M) v = *(const uint4*)(A + gr * K + k0 + ac * 8);
            *(uint4*)(&As[r * 48 + ac * 8]) = v;
        }
        {
            const float* Wp = W + (col0 + bn) * K + k0 + bh * 16;
            unsigned rr[8];
#pragma unroll
            for (int g = 0; g < 8; g++){
                float2 f = *(const float2*)(Wp + g * 2);
                rr[g] = ((unsigned)(unsigned short)f2bf(f.x)) |
                        (((unsigned)(unsigned short)f2bf(f.y)) << 16);
            }
            uint4 lo = {rr[0], rr[1], rr[2], rr[3]};
            uint4 hi = {rr[4], rr[5], rr[6], rr[7]};
            *(uint4*)(&Bs[bn * 48 + bh * 16])     = lo;
            *(uint4*)(&Bs[bn * 48 + bh * 16 + 8]) = hi;
        }
        __syncthreads();

        short8v a[4], b[4];
#pragma unroll
        for (int i = 0; i < 4; i++)
            a[i] = *(const short8v*)(&As[(wr * 64 + i * 16 + l15) * 48 + lkg * 8]);
#pragma unroll
        for (int j = 0; j < 4; j++)
            b[j] = *(const short8v*)(&Bs[(wc * 64 + j * 16 + l15) * 48 + lkg * 8]);
#pragma unroll
        for (int i = 0; i < 4; i++)
#pragma unroll
            for (int j = 0; j < 4; j++)
                acc[i][j] = __builtin_amdgcn_mfma_f32_16x16x32_bf16(a[i], b[j], acc[i][j], 0, 0, 0);
        __syncthreads();
    }

#pragma unroll
    for (int i = 0; i < 4; i++){
#pragma unroll
        for (int q = 0; q < 4; q++){
            long gr = row0 + wr * 64 + i * 16 + lkg * 4 + q;
            if (gr >= M) continue;
#pragma unroll
            for (int j = 0; j < 4; j++){
                long gc = col0 + wc * 64 + j * 16 + l15;
                float v = acc[i][j][q] + bias[gc];
                if (EPI == 1){
                    v = 0.5f * v * (1.f + erff(v * 0.70710678118654752f));
                    Cb[gr * N + gc] = f2bf(v);
                } else if (EPI == 2){
                    Cf[gr * N + gc] = v + Res[gr * N + gc];
                } else {
                    Cf[gr * N + gc] = v;
                }
            }
        }
    }
}

// ============ LayerNorm (two-pass f32) : x f32 -> lnb bf16 ============
__global__ __launch_bounds__(256) void ln_k(const float* __restrict__ x,
    const float* __restrict__ w, const float* __restrict__ b,
    short* __restrict__ y)
{
    __shared__ float red[4];
    int row = blockIdx.x, t = threadIdx.x;
    int lane = t & 63, wid = t >> 6;
    const float* xr = x + (long)row * 768;
    float v0 = xr[t], v1 = xr[t + 256], v2 = xr[t + 512];
    float S = block_reduce_sum_f(v0 + v1 + v2, red, lane, wid);
    float m = S * (1.f / 768.f);
    float d0 = v0 - m, d1 = v1 - m, d2 = v2 - m;
    float Q = block_reduce_sum_f(d0*d0 + d1*d1 + d2*d2, red, lane, wid);
    float rs = 1.f / sqrtf(Q * (1.f / 768.f) + 1e-6f);
    short* yr = y + (long)row * 768;
    yr[t]       = f2bf(d0 * rs * w[t]       + b[t]);
    yr[t + 256] = f2bf(d1 * rs * w[t + 256] + b[t + 256]);
    yr[t + 512] = f2bf(d2 * rs * w[t + 512] + b[t + 512]);
}

// ============ std MHA v2: LDS-tiled, one block per (b,h,32-query tile) ============
// qkv rows: (b*Ntok+n) x 2304 f32 [q|k|v]; o bf16 rows x 768.
__global__ __launch_bounds__(256) void attn_std_v2(
    const float* __restrict__ qkv, short* __restrict__ o, int Ntok)
{
    __shared__ float Ks[202][68];   // stride 68: 16B-aligned rows, conflict-free
    __shared__ float Vs[202][68];
    __shared__ float ps[32][204];
    const int bh = blockIdx.x;
    const int b = bh / HEADS_, h = bh % HEADS_;
    const int qt = blockIdx.y;
    const int t = threadIdx.x;
    const long rb = (long)b * Ntok;
    const float* kb = qkv + rb * 2304 + 768  + h * 64;
    const float* vb = qkv + rb * 2304 + 1536 + h * 64;

    // ---- stage K,V (64 rows/pass, 16 floats/thread) ----
    {
        const int r = t >> 2, c = (t & 3) * 16;
#pragma unroll
        for (int it = 0; it < 4; it++){
            int m = r + it * 64;
            if (m < Ntok){
                const float* krow = kb + (long)m * 2304 + c;
                const float* vrow = vb + (long)m * 2304 + c;
#pragma unroll
                for (int j = 0; j < 4; j++){
                    *(float4*)(&Ks[m][c + j*4]) = *(const float4*)(krow + j*4);
                    *(float4*)(&Vs[m][c + j*4]) = *(const float4*)(vrow + j*4);
                }
            }
        }
    }
    // ---- q row into registers (pre-scaled) ----
    const int qi = t >> 3, s = t & 7;
    const int qg = qt * 32 + qi;
    float4 qv[16];
    if (qg < Ntok){
        const float* qrow = qkv + (rb + qg) * 2304 + h * 64;
#pragma unroll
        for (int j = 0; j < 16; j++){
            float4 v = *(const float4*)(qrow + j*4);
            qv[j].x = v.x * 0.125f; qv[j].y = v.y * 0.125f;
            qv[j].z = v.z * 0.125f; qv[j].w = v.w * 0.125f;
        }
    } else {
#pragma unroll
        for (int j = 0; j < 16; j++) qv[j] = (float4){0.f,0.f,0.f,0.f};
    }
    __syncthreads();

    // ---- scores: 8 lanes per q-row, each covers m = s, s+8, ... ----
    for (int m = s; m < Ntok; m += 8){
        float a = 0.f;
#pragma unroll
        for (int j = 0; j < 16; j++){
            float4 kv = *(const float4*)(&Ks[m][j*4]);
            a += qv[j].x*kv.x + qv[j].y*kv.y + qv[j].z*kv.z + qv[j].w*kv.w;
        }
        ps[qi][m] = a;
    }
    // ---- softmax within the 8-lane group (lanes are wave-contiguous) ----
    float mx = -1e30f;
    for (int m = s; m < Ntok; m += 8) mx = fmaxf(mx, ps[qi][m]);
    mx = fmaxf(mx, __shfl_xor(mx, 1));
    mx = fmaxf(mx, __shfl_xor(mx, 2));
    mx = fmaxf(mx, __shfl_xor(mx, 4));
    float sum = 0.f;
    for (int m = s; m < Ntok; m += 8){
        float e = expf(ps[qi][m] - mx);
        ps[qi][m] = e; sum += e;
    }
    sum += __shfl_xor(sum, 1);
    sum += __shfl_xor(sum, 2);
    sum += __shfl_xor(sum, 4);
    float inv = 1.f / sum;
    for (int m = s; m < Ntok; m += 8) ps[qi][m] *= inv;
    __syncthreads();

    // ---- PV: 2 q-rows x 4 dims per thread ----
    const int qp = t >> 4, ds = (t & 15) * 4;
    const int r0 = 2 * qp, r1 = 2 * qp + 1;
    float4 A0 = {0.f,0.f,0.f,0.f}, A1 = {0.f,0.f,0.f,0.f};
    for (int m = 0; m < Ntok; m++){
        float4 v = *(const float4*)(&Vs[m][ds]);
        float p0 = ps[r0][m], p1 = ps[r1][m];
        A0.x += p0*v.x; A0.y += p0*v.y; A0.z += p0*v.z; A0.w += p0*v.w;
        A1.x += p1*v.x; A1.y += p1*v.y; A1.z += p1*v.z; A1.w += p1*v.w;
    }
    const int n0 = qt * 32 + r0;
    if (n0 < Ntok){
        uint2 wv;
        wv.x = (unsigned)(unsigned short)f2bf(A0.x) | (((unsigned)(unsigned short)f2bf(A0.y)) << 16);
        wv.y = (unsigned)(unsigned short)f2bf(A0.z) | (((unsigned)(unsigned short)f2bf(A0.w)) << 16);
        *(uint2*)(o + (rb + n0) * 768 + h * 64 + ds) = wv;
    }
    if (n0 + 1 < Ntok){
        uint2 wv;
        wv.x = (unsigned)(unsigned short)f2bf(A1.x) | (((unsigned)(unsigned short)f2bf(A1.y)) << 16);
        wv.y = (unsigned)(unsigned short)f2bf(A1.z) | (((unsigned)(unsigned short)f2bf(A1.w)) << 16);
        *(uint2*)(o + (rb + n0 + 1) * 768 + h * 64 + ds) = wv;
    }
}

// ============ deep attention v2: wave-per-key QK, coalesced, scramble folded ============
// Writes bf16 directly at out[b][d*197 + n] (== reference swapaxes+reshape).
__global__ __launch_bounds__(256) void attn_deep_v2(
    const float* __restrict__ qkv, const float* __restrict__ prompts,
    const int* __restrict__ selm, short* __restrict__ o, int li)
{
    __shared__ float q[768];
    __shared__ float sc[256];
    __shared__ float red[256];
    const int b = blockIdx.x, n = blockIdx.y, t = threadIdx.x;
    const int lane = t & 63, w = t >> 6;
    const float* qr = qkv + (long)(b * NT_ + n) * 2304;
    q[t] = qr[t]; q[t + 256] = qr[t + 256]; q[t + 512] = qr[t + 512];
    __syncthreads();

    const float4 q0 = *(const float4*)(&q[lane * 4]);
    const float4 q1 = *(const float4*)(&q[256 + lane * 4]);
    const float4 q2 = *(const float4*)(&q[512 + lane * 4]);

    const float* kp = prompts + ((long)selm[b] * 6 + 2 * li) * 5 * 768;
    const float* vp = kp + 5 * 768;

    // QK^T: one wave per key, lanes cover d = j*256 + lane*4 (coalesced)
    for (int m = w; m < 202; m += 4){
        const float* kr = (m < 5) ? (kp + (long)m * 768)
                                  : (qkv + (long)(b * NT_ + (m - 5)) * 2304 + 768);
        float4 k0 = *(const float4*)(kr + lane * 4);
        float4 k1 = *(const float4*)(kr + 256 + lane * 4);
        float4 k2 = *(const float4*)(kr + 512 + lane * 4);
        float a = q0.x*k0.x + q0.y*k0.y + q0.z*k0.z + q0.w*k0.w
                + q1.x*k1.x + q1.y*k1.y + q1.z*k1.z + q1.w*k1.w
                + q2.x*k2.x + q2.y*k2.y + q2.z*k2.z + q2.w*k2.w;
#pragma unroll
        for (int off = 32; off; off >>= 1) a += __shfl_xor(a, off);
        if (lane == 0) sc[m] = a * 0.125f;
    }
    __syncthreads();

    // softmax over 202 (verified tree)
    float s = (t < 202) ? sc[t] : -1e30f;
    red[t] = s; __syncthreads();
    for (int wd = 128; wd; wd >>= 1){ if (t < wd) red[t] = fmaxf(red[t], red[t+wd]); __syncthreads(); }
    float mx = red[0]; __syncthreads();
    float e = (t < 202) ? expf(s - mx) : 0.f;
    red[t] = e; __syncthreads();
    for (int wd = 128; wd; wd >>= 1){ if (t < wd) red[t] += red[t+wd]; __syncthreads(); }
    float inv = 1.f / red[0];
    __syncthreads();
    sc[t] = e * inv;
    __syncthreads();

    // PV (coalesced V reads) + transposed bf16 write
    float a0 = 0.f, a1 = 0.f, a2 = 0.f;
    for (int m = 0; m < 5; m++){
        const float* vr = vp + (long)m * 768;
        float pm = sc[m];
        a0 += pm * vr[t]; a1 += pm * vr[t + 256]; a2 += pm * vr[t + 512];
    }
    for (int m = 5; m < 202; m++){
        const float* vr = qkv + (long)(b * NT_ + (m - 5)) * 2304 + 1536;
        float pm = sc[m];
        a0 += pm * vr[t]; a1 += pm * vr[t + 256]; a2 += pm * vr[t + 512];
    }
    short* ob = o + (long)b * NT_ * 768 + n;   // out[b][d*197 + n]
    ob[(long)t * 197]         = f2bf(a0);
    ob[(long)(t + 256) * 197] = f2bf(a1);
    ob[(long)(t + 512) * 197] = f2bf(a2);
}

// ============ patch unfold (f32 -> bf16) ============
__global__ void unfold_k(const float* __restrict__ in, short* __restrict__ out){
    long i = (long)blockIdx.x * 256 + threadIdx.x;
    long total = (long)B_ * 196 * 768;
    if (i >= total) return;
    int f = (int)(i % 768); long rw = i / 768;
    int t = (int)(rw % 196); int b = (int)(rw / 196);
    int gy = t / 14, gx = t % 14;
    int c = f >> 8, rem = f & 255, py = rem >> 4, px = rem & 15;
    out[i] = f2bf(in[(((long)(b * 3 + c) * 224) + gy * 16 + py) * 224 + gx * 16 + px]);
}

// ============ assemble x0 = [cls+pos ; patches+pos] (f32) ============
__global__ void assemble_k(const float* __restrict__ pe, const float* __restrict__ cls,
    const float* __restrict__ pos, float* __restrict__ x0){
    long i = (long)blockIdx.x * 256 + threadIdx.x;
    long total = (long)B_ * NT_ * 768;
    if (i >= total) return;
    int d = (int)(i % 768); long rw = i / 768;
    int n = (int)(rw % NT_); int b = (int)(rw / NT_);
    float v;
    if (n == 0) v = cls[d] + pos[d];
    else        v = pe[((long)b * 196 + (n - 1)) * 768 + d] + pos[(long)n * 768 + d];
    x0[i] = v;
}

__global__ void copy_f(const float* __restrict__ a, float* __restrict__ b, long total){
    long i = (long)blockIdx.x * 256 + threadIdx.x;
    if (i < total) b[i] = a[i];
}

// ============ build sub-branch rows (insert 5 prompt tokens after CLS) ============
__global__ void build_sub_k(const float* __restrict__ x0, const float* __restrict__ subp,
    const float* __restrict__ pos, float* __restrict__ xSub){
    long i = (long)blockIdx.x * 256 + threadIdx.x;
    long total = (long)B_ * NS_ * 768;
    if (i >= total) return;
    int d = (int)(i % 768); long rw = i / 768;
    int n = (int)(rw % NS_); int b = (int)(rw / NS_);
    float v;
    if (n == 0)      v = x0[((long)b * NT_) * 768 + d];
    else if (n <= 5) v = subp[(n - 1) * 768 + d] + pos[d];
    else             v = x0[((long)b * NT_ + (n - 5)) * 768 + d];
    xSub[i] = v;
}

// ============ routing (f64 internals, f32 data) ============
__global__ __launch_bounds__(256) void select_k(
    const float* __restrict__ xA, const float* __restrict__ norm_w,
    const float* __restrict__ norm_b, const float* __restrict__ main_key,
    const float* __restrict__ sub_key, const int* __restrict__ task_id_p,
    int* __restrict__ selm, int* __restrict__ flag)
{
    __shared__ double red[4];
    int b = blockIdx.x, t = threadIdx.x, lane = t & 63, wid = t >> 6;
    const float* xr = xA + (long)b * NT_ * 768;
    double v0 = xr[t], v1 = xr[t + 256], v2 = xr[t + 512];
    double S = block_reduce_sum_d(v0 + v1 + v2, red, lane, wid);
    double m = S * (1.0 / 768.0);
    double d0 = v0 - m, d1 = v1 - m, d2 = v2 - m;
    double Q = block_reduce_sum_d(d0*d0 + d1*d1 + d2*d2, red, lane, wid);
    double rs = 1.0 / sqrt(Q * (1.0 / 768.0) + 1e-6);
    double q0 = d0 * rs * (double)norm_w[t]       + (double)norm_b[t];
    double q1 = d1 * rs * (double)norm_w[t + 256] + (double)norm_b[t + 256];
    double q2 = d2 * rs * (double)norm_w[t + 512] + (double)norm_b[t + 512];
    double qn = block_reduce_sum_d(q0*q0 + q1*q1 + q2*q2, red, lane, wid);
    double qinv = 1.0 / sqrt(fmax(qn, 1e-12));

    int tk = *task_id_p;
    int ncand = tk + 2;
    double best = -1e300; int bsel = 0;
    for (int c = 0; c < ncand; c++){
        const float* cr = (c <= tk) ? (main_key + (long)c * 768) : sub_key;
        double c0 = cr[t], c1 = cr[t + 256], c2 = cr[t + 512];
        double dotq = block_reduce_sum_d(q0*c0 + q1*c1 + q2*c2, red, lane, wid);
        double nc   = block_reduce_sum_d(c0*c0 + c1*c1 + c2*c2, red, lane, wid);
        double sim = dotq * qinv * (1.0 / sqrt(fmax(nc, 1e-12)));
        if (sim > best){ best = sim; bsel = c; }
    }
    if (t == 0){
        int isMain = (bsel <= tk) ? 1 : 0;
        selm[b] = isMain ? bsel : 0;
        flag[b] = isMain;
    }
}

// ============ final head (f64 internals, f32 data, f32 out) ============
__global__ __launch_bounds__(256) void head_k(
    const float* __restrict__ xM, const float* __restrict__ xSub,
    const float* __restrict__ norm_w, const float* __restrict__ norm_b,
    const float* __restrict__ fc_w, const float* __restrict__ fc_b,
    const int* __restrict__ flag, float* __restrict__ out)
{
    __shared__ double vec[768];
    __shared__ double red[4];
    int b = blockIdx.x, t = threadIdx.x, lane = t & 63, wid = t >> 6;
    int isMain = flag[b];
    double a0 = 0.0, a1 = 0.0, a2 = 0.0;
    int nrows = isMain ? 1 : 5;
    for (int rI = 0; rI < nrows; rI++){
        const float* xr = isMain ? (xM + (long)b * NT_ * 768)
                                 : (xSub + ((long)b * NS_ + 1 + rI) * 768);
        double v0 = xr[t], v1 = xr[t + 256], v2 = xr[t + 512];
        double S = block_reduce_sum_d(v0 + v1 + v2, red, lane, wid);
        double m = S * (1.0 / 768.0);
        double d0 = v0 - m, d1 = v1 - m, d2 = v2 - m;
        double Q = block_reduce_sum_d(d0*d0 + d1*d1 + d2*d2, red, lane, wid);
        double rs = 1.0 / sqrt(Q * (1.0 / 768.0) + 1e-6);
        a0 += d0 * rs * (double)norm_w[t]       + (double)norm_b[t];
        a1 += d1 * rs * (double)norm_w[t + 256] + (double)norm_b[t + 256];
        a2 += d2 * rs * (double)norm_w[t + 512] + (double)norm_b[t + 512];
    }
    double scl = isMain ? 1.0 : 0.2;
    vec[t] = a0 * scl; vec[t + 256] = a1 * scl; vec[t + 512] = a2 * scl;
    __syncthreads();
    if (t < NCLS_){
        const float* wr = fc_w + (long)t * 768;
        double acc = (double)fc_b[t];
#pragma unroll 8
        for (int j = 0; j < 768; j++) acc += vec[j] * (double)wr[j];
        out[b * NCLS_ + t] = (float)acc;
    }
}

// ================= host-side =================
struct Params {
    const float *qkv_w, *qkv_b, *proj_w, *proj_b;
    const float *ln1_w, *ln1_b, *ln2_w, *ln2_b;
    const float *fc1_w, *fc1_b, *fc2_w, *fc2_b;
    const float *prompts; const int* selm;
    short *lnb, *attb, *hidb;
    float *qkvb;
};

// mode 0: concat (std attn on both segments)  mode 1: main std  mode 2: main deep
static void run_layer(hipStream_t st, float* x, int M, int layer, int mode, int li,
                      const Params& P)
{
    int gy = (M + 127) / 128;
    ln_k<<<M, 256, 0, st>>>(x, P.ln1_w + layer * 768, P.ln1_b + layer * 768, P.lnb);
    gemm_bf16<0><<<dim3(2304 / 128, gy), 256, 0, st>>>(P.lnb,
        P.qkv_w + (long)layer * 2304 * 768, P.qkv_b + layer * 2304, nullptr,
        P.qkvb, nullptr, M, 768, 2304);
    if (mode == 0){
        attn_std_v2<<<dim3(B_ * HEADS_, 7), 256, 0, st>>>(P.qkvb, P.attb, NT_);
        attn_std_v2<<<dim3(B_ * HEADS_, 7), 256, 0, st>>>(
            P.qkvb + (long)MROW_ * 2304, P.attb + (long)MROW_ * 768, NS_);
    } else if (mode == 1){
        attn_std_v2<<<dim3(B_ * HEADS_, 7), 256, 0, st>>>(P.qkvb, P.attb, NT_);
    } else {
        attn_deep_v2<<<dim3(B_, NT_), 256, 0, st>>>(P.qkvb, P.prompts, P.selm, P.attb, li);
    }
    gemm_bf16<2><<<dim3(768 / 128, gy), 256, 0, st>>>(P.attb,
        P.proj_w + (long)layer * 768 * 768, P.proj_b + layer * 768, x,
        x, nullptr, M, 768, 768);
    ln_k<<<M, 256, 0, st>>>(x, P.ln2_w + layer * 768, P.ln2_b + layer * 768, P.lnb);
    gemm_bf16<1><<<dim3(3072 / 128, gy), 256, 0, st>>>(P.lnb,
        P.fc1_w + (long)layer * 3072 * 768, P.fc1_b + layer * 3072, nullptr,
        nullptr, P.hidb, M, 768, 3072);
    gemm_bf16<2><<<dim3(768 / 128, gy), 256, 0, st>>>(P.hidb,
        P.fc2_w + (long)layer * 768 * 3072, P.fc2_b + layer * 768, x,
        x, nullptr, M, 3072, 768);
}

extern "C" void kernel_launch(void* const* d_in, const int* in_sizes, int n_in,
                              void* d_out, int out_size, void* d_ws, size_t ws_size,
                              hipStream_t stream)
{
    (void)in_sizes; (void)n_in; (void)out_size; (void)ws_size;
    const float* inputs   = (const float*)d_in[0];
    const int*   task_id  = (const int*)  d_in[1];
    const float* patch_w  = (const float*)d_in[2];
    const float* patch_b  = (const float*)d_in[3];
    const float* cls_tok  = (const float*)d_in[4];
    const float* pos      = (const float*)d_in[5];
    const float* qkv_w    = (const float*)d_in[6];
    const float* qkv_b    = (const float*)d_in[7];
    const float* proj_w   = (const float*)d_in[8];
    const float* proj_b   = (const float*)d_in[9];
    const float* ln1_w    = (const float*)d_in[10];
    const float* ln1_b    = (const float*)d_in[11];
    const float* ln2_w    = (const float*)d_in[12];
    const float* ln2_b    = (const float*)d_in[13];
    const float* fc1_w    = (const float*)d_in[14];
    const float* fc1_b    = (const float*)d_in[15];
    const float* fc2_w    = (const float*)d_in[16];
    const float* fc2_b    = (const float*)d_in[17];
    const float* norm_w   = (const float*)d_in[18];
    const float* norm_b   = (const float*)d_in[19];
    const float* fc_w     = (const float*)d_in[20];
    const float* fc_b     = (const float*)d_in[21];
    const float* main_key = (const float*)d_in[22];
    const float* sub_key  = (const float*)d_in[23];
    const float* m_prompts= (const float*)d_in[24];
    const float* s_prompt = (const float*)d_in[25];
    float* out = (float*)d_out;

    char* wsb = (char*)d_ws;
    size_t off = 0;
    auto allocB = [&](size_t bytes) -> void* {
        void* p = (void*)(wsb + off);
        off += (bytes + 255) & ~(size_t)255;
        return p;
    };
    float* x0   = (float*)allocB((size_t)MROW_ * 768 * 4);
    float* xC   = (float*)allocB((size_t)CROW_ * 768 * 4);
    float* xM   = (float*)allocB((size_t)MROW_ * 768 * 4);
    short* lnb  = (short*)allocB((size_t)CROW_ * 768 * 2);
    short* attb = (short*)allocB((size_t)CROW_ * 768 * 2);
    float* qkvb = (float*)allocB((size_t)CROW_ * 2304 * 4);
    short* hidb = (short*)allocB((size_t)CROW_ * 3072 * 2);
    int*   selm = (int*)allocB(64);
    int*   flag = (int*)allocB(64);

    Params P;
    P.qkv_w = qkv_w; P.qkv_b = qkv_b; P.proj_w = proj_w; P.proj_b = proj_b;
    P.ln1_w = ln1_w; P.ln1_b = ln1_b; P.ln2_w = ln2_w; P.ln2_b = ln2_b;
    P.fc1_w = fc1_w; P.fc1_b = fc1_b; P.fc2_w = fc2_w; P.fc2_b = fc2_b;
    P.prompts = m_prompts; P.selm = selm;
    P.lnb = lnb; P.attb = attb; P.hidb = hidb; P.qkvb = qkvb;

    const long XN = (long)MROW_ * 768;

    // -------- patch embed --------
    {
        long tot = (long)B_ * 196 * 768;
        short* un  = hidb;            // embed-phase scratch
        float* peo = qkvb;
        unfold_k<<<(int)((tot + 255) / 256), 256, 0, stream>>>(inputs, un);
        gemm_bf16<0><<<dim3(768 / 128, (3136 + 127) / 128), 256, 0, stream>>>(
            un, patch_w, patch_b, nullptr, peo, nullptr, 3136, 768, 768);
        assemble_k<<<(int)((XN + 255) / 256), 256, 0, stream>>>(peo, cls_tok, pos, x0);
        copy_f<<<(int)((XN + 255) / 256), 256, 0, stream>>>(x0, xC, XN);
        long st = (long)SROW_ * 768;
        build_sub_k<<<(int)((st + 255) / 256), 256, 0, stream>>>(x0, s_prompt, pos,
                                                                 xC + (long)MROW_ * 768);
    }

    // -------- concatenated pass A + sub branch --------
    for (int i = 0; i < DEPTH_; i++){
        run_layer(stream, xC, CROW_, i, 0, 0, P);
        if (i == 1)
            copy_f<<<(int)((XN + 255) / 256), 256, 0, stream>>>(xC, xM, XN);
    }

    // -------- routing --------
    select_k<<<16, 256, 0, stream>>>(xC, norm_w, norm_b, main_key, sub_key,
                                     task_id, selm, flag);

    // -------- main branch layers 2..11 (deep prompts at 2,3,4) --------
    for (int i = 2; i < DEPTH_; i++){
        int mode = (i >= 2 && i <= 4) ? 2 : 1;
        run_layer(stream, xM, MROW_, i, mode, i - 2, P);
    }

    // -------- heads + per-sample select --------
    head_k<<<16, 256, 0, stream>>>(xM, xC + (long)MROW_ * 768, norm_w, norm_b,
                                   fc_w, fc_b, flag, out);
}

// Round 8
// 9165.767 us; speedup vs baseline: 9.8441x; 1.2952x over previous
//
#include <hip/hip_runtime.h>
#include <math.h>

// ---------------- constants ----------------
#define B_    16
#define NT_   197
#define NS_   202
#define HEADS_ 12
#define DEPTH_ 12
#define NCLS_ 100
#define MROW_ (B_ * NT_)      // 3152
#define SROW_ (B_ * NS_)      // 3232
#define CROW_ (MROW_ + SROW_) // 6384

typedef __attribute__((ext_vector_type(8))) short short8v;
typedef __attribute__((ext_vector_type(4))) float f32x4;

// f32 -> bf16 bits (RNE)
__device__ __forceinline__ short f2bf(float f){
    unsigned u = __builtin_bit_cast(unsigned, f);
    unsigned r = (u + 0x7FFFu + ((u >> 16) & 1u)) >> 16;
    return (short)r;
}

// ============ float block reduce (256 thr) ============
__device__ __forceinline__ float block_reduce_sum_f(float s, float* red, int lane, int wid){
#pragma unroll
    for (int off = 32; off; off >>= 1) s += __shfl_xor(s, off);
    if (lane == 0) red[wid] = s;
    __syncthreads();
    float S = red[0] + red[1] + red[2] + red[3];
    __syncthreads();
    return S;
}
// ============ double block reduce (256 thr) — routing/head only ============
__device__ __forceinline__ double block_reduce_sum_d(double s, double* red, int lane, int wid){
#pragma unroll
    for (int off = 32; off; off >>= 1) s += __shfl_xor(s, off);
    if (lane == 0) red[wid] = s;
    __syncthreads();
    double S = red[0] + red[1] + red[2] + red[3];
    __syncthreads();
    return S;
}

// ============ weight convert f32 -> bf16 (8 elems/thread, grid-stride) ============
__global__ void convert_w_k(const float* __restrict__ in, short* __restrict__ out, long n){
    long i = ((long)blockIdx.x * 256 + threadIdx.x) * 8;
    long stride = (long)gridDim.x * 256 * 8;
    for (; i < n; i += stride){
        float4 a = *(const float4*)(in + i);
        float4 b = *(const float4*)(in + i + 4);
        uint4 o4;
        o4.x = (unsigned)(unsigned short)f2bf(a.x) | (((unsigned)(unsigned short)f2bf(a.y)) << 16);
        o4.y = (unsigned)(unsigned short)f2bf(a.z) | (((unsigned)(unsigned short)f2bf(a.w)) << 16);
        o4.z = (unsigned)(unsigned short)f2bf(b.x) | (((unsigned)(unsigned short)f2bf(b.y)) << 16);
        o4.w = (unsigned)(unsigned short)f2bf(b.z) | (((unsigned)(unsigned short)f2bf(b.w)) << 16);
        *(uint4*)(out + i) = o4;
    }
}

// ============ bf16 MFMA GEMM: C = A @ W^T + bias (+epilogue) ============
// A: M x K bf16. W: f32 (WB=0, converted in staging) or bf16 (WB=1, pre-cached).
// EPI 0: Cf f32. EPI 1: exact GELU -> Cb bf16. EPI 2: Cf = Res + .. (f32).
template<int EPI, int WB>
__global__ __launch_bounds__(256) void gemm_bf16(
    const short* __restrict__ A, const void* __restrict__ Wv,
    const float* __restrict__ bias, const float* __restrict__ Res,
    float* __restrict__ Cf, short* __restrict__ Cb, int M, int K, int N)
{
    __shared__ short As[128 * 48];
    __shared__ short Bs[128 * 48];
    const int t = threadIdx.x;
    const int lane = t & 63, wid = t >> 6;
    const int wr = wid >> 1, wc = wid & 1;
    const long row0 = (long)blockIdx.y * 128;
    const long col0 = (long)blockIdx.x * 128;

    f32x4 acc[4][4];
#pragma unroll
    for (int i = 0; i < 4; i++)
#pragma unroll
        for (int j = 0; j < 4; j++) acc[i][j] = (f32x4){0.f, 0.f, 0.f, 0.f};

    const int l15 = lane & 15, lkg = lane >> 4;
    const int ar = t >> 2, ac = t & 3;
    const int bn = t >> 1, bh = t & 1;

    for (int k0 = 0; k0 < K; k0 += 32){
#pragma unroll
        for (int it = 0; it < 2; it++){
            int r = ar + it * 64;
            long gr = row0 + r;
            uint4 v = {0u, 0u, 0u, 0u};
            if (gr < M) v = *(const uint4*)(A + gr * K + k0 + ac * 8);
            *(uint4*)(&As[r * 48 + ac * 8]) = v;
        }
        if (WB == 1){
            const short* Wb = (const short*)Wv;
            const short* Wp = Wb + (col0 + bn) * K + k0 + bh * 16;
            uint4 lo = *(const uint4*)(Wp);
            uint4 hi = *(const uint4*)(Wp + 8);
            *(uint4*)(&Bs[bn * 48 + bh * 16])     = lo;
            *(uint4*)(&Bs[bn * 48 + bh * 16 + 8]) = hi;
        } else {
            const float* Wf = (const float*)Wv;
            const float* Wp = Wf + (col0 + bn) * K + k0 + bh * 16;
            unsigned rr[8];
#pragma unroll
            for (int g = 0; g < 8; g++){
                float2 f = *(const float2*)(Wp + g * 2);
                rr[g] = ((unsigned)(unsigned short)f2bf(f.x)) |
                        (((unsigned)(unsigned short)f2bf(f.y)) << 16);
            }
            uint4 lo = {rr[0], rr[1], rr[2], rr[3]};
            uint4 hi = {rr[4], rr[5], rr[6], rr[7]};
            *(uint4*)(&Bs[bn * 48 + bh * 16])     = lo;
            *(uint4*)(&Bs[bn * 48 + bh * 16 + 8]) = hi;
        }
        __syncthreads();

        short8v a[4], b[4];
#pragma unroll
        for (int i = 0; i < 4; i++)
            a[i] = *(const short8v*)(&As[(wr * 64 + i * 16 + l15) * 48 + lkg * 8]);
#pragma unroll
        for (int j = 0; j < 4; j++)
            b[j] = *(const short8v*)(&Bs[(wc * 64 + j * 16 + l15) * 48 + lkg * 8]);
#pragma unroll
        for (int i = 0; i < 4; i++)
#pragma unroll
            for (int j = 0; j < 4; j++)
                acc[i][j] = __builtin_amdgcn_mfma_f32_16x16x32_bf16(a[i], b[j], acc[i][j], 0, 0, 0);
        __syncthreads();
    }

#pragma unroll
    for (int i = 0; i < 4; i++){
#pragma unroll
        for (int q = 0; q < 4; q++){
            long gr = row0 + wr * 64 + i * 16 + lkg * 4 + q;
            if (gr >= M) continue;
#pragma unroll
            for (int j = 0; j < 4; j++){
                long gc = col0 + wc * 64 + j * 16 + l15;
                float v = acc[i][j][q] + bias[gc];
                if (EPI == 1){
                    v = 0.5f * v * (1.f + erff(v * 0.70710678118654752f));
                    Cb[gr * N + gc] = f2bf(v);
                } else if (EPI == 2){
                    Cf[gr * N + gc] = v + Res[gr * N + gc];
                } else {
                    Cf[gr * N + gc] = v;
                }
            }
        }
    }
}

// ============ LayerNorm (two-pass f32) : x f32 -> lnb bf16 ============
__global__ __launch_bounds__(256) void ln_k(const float* __restrict__ x,
    const float* __restrict__ w, const float* __restrict__ b,
    short* __restrict__ y)
{
    __shared__ float red[4];
    int row = blockIdx.x, t = threadIdx.x;
    int lane = t & 63, wid = t >> 6;
    const float* xr = x + (long)row * 768;
    float v0 = xr[t], v1 = xr[t + 256], v2 = xr[t + 512];
    float S = block_reduce_sum_f(v0 + v1 + v2, red, lane, wid);
    float m = S * (1.f / 768.f);
    float d0 = v0 - m, d1 = v1 - m, d2 = v2 - m;
    float Q = block_reduce_sum_f(d0*d0 + d1*d1 + d2*d2, red, lane, wid);
    float rs = 1.f / sqrtf(Q * (1.f / 768.f) + 1e-6f);
    short* yr = y + (long)row * 768;
    yr[t]       = f2bf(d0 * rs * w[t]       + b[t]);
    yr[t + 256] = f2bf(d1 * rs * w[t + 256] + b[t + 256]);
    yr[t + 512] = f2bf(d2 * rs * w[t + 512] + b[t + 512]);
}

// ============ std MHA v3: one 512-thr block per (b,h); K/V staged once ============
// qkv rows: (row) x 2304 f32 [q|k|v]; o bf16 rows x 768.
// blockIdx.y selects segment (dual-segment mode): 0 -> (qkv0,o0,N0), 1 -> (qkv1,o1,N1).
__global__ __launch_bounds__(512) void attn_std_v3(
    const float* __restrict__ qkv0, short* __restrict__ o0, int N0,
    const float* __restrict__ qkv1, short* __restrict__ o1, int N1)
{
    __shared__ float Ks[202][68];
    __shared__ float Vs[202][68];
    __shared__ float ps[64][203];
    const int bh = blockIdx.x;
    const int b = bh / HEADS_, h = bh % HEADS_;
    const int seg = blockIdx.y;
    const float* qkv = seg ? qkv1 : qkv0;
    short* o = seg ? o1 : o0;
    const int Ntok = seg ? N1 : N0;
    const int t = threadIdx.x;
    const long rb = (long)b * Ntok;
    const float* kb = qkv + rb * 2304 + 768  + h * 64;
    const float* vb = qkv + rb * 2304 + 1536 + h * 64;

    // ---- stage K,V once (128 rows/pass x 2) ----
    {
        const int r = t >> 2, c = (t & 3) * 16;
#pragma unroll
        for (int it = 0; it < 2; it++){
            int m = r + it * 128;
            if (m < Ntok){
                const float* krow = kb + (long)m * 2304 + c;
                const float* vrow = vb + (long)m * 2304 + c;
#pragma unroll
                for (int j = 0; j < 4; j++){
                    *(float4*)(&Ks[m][c + j*4]) = *(const float4*)(krow + j*4);
                    *(float4*)(&Vs[m][c + j*4]) = *(const float4*)(vrow + j*4);
                }
            }
        }
    }
    __syncthreads();

    const int qi = t >> 3, s = t & 7;      // 64 q-rows, 8 lanes each
    const int qp = t >> 4, ds = (t & 15) * 4;  // PV: 2 rows x 4 dims
    const int nqt = (Ntok + 63) / 64;

    for (int qt = 0; qt < nqt; qt++){
        // ---- q row into registers (pre-scaled) ----
        const int qg = qt * 64 + qi;
        float4 qv[16];
        if (qg < Ntok){
            const float* qrow = qkv + (rb + qg) * 2304 + h * 64;
#pragma unroll
            for (int j = 0; j < 16; j++){
                float4 v = *(const float4*)(qrow + j*4);
                qv[j].x = v.x * 0.125f; qv[j].y = v.y * 0.125f;
                qv[j].z = v.z * 0.125f; qv[j].w = v.w * 0.125f;
            }
        } else {
#pragma unroll
            for (int j = 0; j < 16; j++) qv[j] = (float4){0.f,0.f,0.f,0.f};
        }

        // ---- scores ----
        for (int m = s; m < Ntok; m += 8){
            float a = 0.f;
#pragma unroll
            for (int j = 0; j < 16; j++){
                float4 kv = *(const float4*)(&Ks[m][j*4]);
                a += qv[j].x*kv.x + qv[j].y*kv.y + qv[j].z*kv.z + qv[j].w*kv.w;
            }
            ps[qi][m] = a;
        }
        // ---- softmax within 8-lane group ----
        float mx = -1e30f;
        for (int m = s; m < Ntok; m += 8) mx = fmaxf(mx, ps[qi][m]);
        mx = fmaxf(mx, __shfl_xor(mx, 1));
        mx = fmaxf(mx, __shfl_xor(mx, 2));
        mx = fmaxf(mx, __shfl_xor(mx, 4));
        float sum = 0.f;
        for (int m = s; m < Ntok; m += 8){
            float e = expf(ps[qi][m] - mx);
            ps[qi][m] = e; sum += e;
        }
        sum += __shfl_xor(sum, 1);
        sum += __shfl_xor(sum, 2);
        sum += __shfl_xor(sum, 4);
        float inv = 1.f / sum;
        for (int m = s; m < Ntok; m += 8) ps[qi][m] *= inv;
        __syncthreads();

        // ---- PV: 2 q-rows x 4 dims per thread ----
        const int r0 = 2 * qp, r1 = 2 * qp + 1;
        float4 A0 = {0.f,0.f,0.f,0.f}, A1 = {0.f,0.f,0.f,0.f};
        for (int m = 0; m < Ntok; m++){
            float4 v = *(const float4*)(&Vs[m][ds]);
            float p0 = ps[r0][m], p1 = ps[r1][m];
            A0.x += p0*v.x; A0.y += p0*v.y; A0.z += p0*v.z; A0.w += p0*v.w;
            A1.x += p1*v.x; A1.y += p1*v.y; A1.z += p1*v.z; A1.w += p1*v.w;
        }
        const int n0 = qt * 64 + r0;
        if (n0 < Ntok){
            uint2 wv;
            wv.x = (unsigned)(unsigned short)f2bf(A0.x) | (((unsigned)(unsigned short)f2bf(A0.y)) << 16);
            wv.y = (unsigned)(unsigned short)f2bf(A0.z) | (((unsigned)(unsigned short)f2bf(A0.w)) << 16);
            *(uint2*)(o + (rb + n0) * 768 + h * 64 + ds) = wv;
        }
        if (n0 + 1 < Ntok){
            uint2 wv;
            wv.x = (unsigned)(unsigned short)f2bf(A1.x) | (((unsigned)(unsigned short)f2bf(A1.y)) << 16);
            wv.y = (unsigned)(unsigned short)f2bf(A1.z) | (((unsigned)(unsigned short)f2bf(A1.w)) << 16);
            *(uint2*)(o + (rb + n0 + 1) * 768 + h * 64 + ds) = wv;
        }
        __syncthreads();   // ps reused next tile
    }
}

// ============ deep attention v2 (unchanged, verified) ============
__global__ __launch_bounds__(256) void attn_deep_v2(
    const float* __restrict__ qkv, const float* __restrict__ prompts,
    const int* __restrict__ selm, short* __restrict__ o, int li)
{
    __shared__ float q[768];
    __shared__ float sc[256];
    __shared__ float red[256];
    const int b = blockIdx.x, n = blockIdx.y, t = threadIdx.x;
    const int lane = t & 63, w = t >> 6;
    const float* qr = qkv + (long)(b * NT_ + n) * 2304;
    q[t] = qr[t]; q[t + 256] = qr[t + 256]; q[t + 512] = qr[t + 512];
    __syncthreads();

    const float4 q0 = *(const float4*)(&q[lane * 4]);
    const float4 q1 = *(const float4*)(&q[256 + lane * 4]);
    const float4 q2 = *(const float4*)(&q[512 + lane * 4]);

    const float* kp = prompts + ((long)selm[b] * 6 + 2 * li) * 5 * 768;
    const float* vp = kp + 5 * 768;

    for (int m = w; m < 202; m += 4){
        const float* kr = (m < 5) ? (kp + (long)m * 768)
                                  : (qkv + (long)(b * NT_ + (m - 5)) * 2304 + 768);
        float4 k0 = *(const float4*)(kr + lane * 4);
        float4 k1 = *(const float4*)(kr + 256 + lane * 4);
        float4 k2 = *(const float4*)(kr + 512 + lane * 4);
        float a = q0.x*k0.x + q0.y*k0.y + q0.z*k0.z + q0.w*k0.w
                + q1.x*k1.x + q1.y*k1.y + q1.z*k1.z + q1.w*k1.w
                + q2.x*k2.x + q2.y*k2.y + q2.z*k2.z + q2.w*k2.w;
#pragma unroll
        for (int off = 32; off; off >>= 1) a += __shfl_xor(a, off);
        if (lane == 0) sc[m] = a * 0.125f;
    }
    __syncthreads();

    float s = (t < 202) ? sc[t] : -1e30f;
    red[t] = s; __syncthreads();
    for (int wd = 128; wd; wd >>= 1){ if (t < wd) red[t] = fmaxf(red[t], red[t+wd]); __syncthreads(); }
    float mx = red[0]; __syncthreads();
    float e = (t < 202) ? expf(s - mx) : 0.f;
    red[t] = e; __syncthreads();
    for (int wd = 128; wd; wd >>= 1){ if (t < wd) red[t] += red[t+wd]; __syncthreads(); }
    float inv = 1.f / red[0];
    __syncthreads();
    sc[t] = e * inv;
    __syncthreads();

    float a0 = 0.f, a1 = 0.f, a2 = 0.f;
    for (int m = 0; m < 5; m++){
        const float* vr = vp + (long)m * 768;
        float pm = sc[m];
        a0 += pm * vr[t]; a1 += pm * vr[t + 256]; a2 += pm * vr[t + 512];
    }
    for (int m = 5; m < 202; m++){
        const float* vr = qkv + (long)(b * NT_ + (m - 5)) * 2304 + 1536;
        float pm = sc[m];
        a0 += pm * vr[t]; a1 += pm * vr[t + 256]; a2 += pm * vr[t + 512];
    }
    short* ob = o + (long)b * NT_ * 768 + n;
    ob[(long)t * 197]         = f2bf(a0);
    ob[(long)(t + 256) * 197] = f2bf(a1);
    ob[(long)(t + 512) * 197] = f2bf(a2);
}

// ============ patch unfold (f32 -> bf16) ============
__global__ void unfold_k(const float* __restrict__ in, short* __restrict__ out){
    long i = (long)blockIdx.x * 256 + threadIdx.x;
    long total = (long)B_ * 196 * 768;
    if (i >= total) return;
    int f = (int)(i % 768); long rw = i / 768;
    int t = (int)(rw % 196); int b = (int)(rw / 196);
    int gy = t / 14, gx = t % 14;
    int c = f >> 8, rem = f & 255, py = rem >> 4, px = rem & 15;
    out[i] = f2bf(in[(((long)(b * 3 + c) * 224) + gy * 16 + py) * 224 + gx * 16 + px]);
}

// ============ assemble x0 = [cls+pos ; patches+pos] (f32) ============
__global__ void assemble_k(const float* __restrict__ pe, const float* __restrict__ cls,
    const float* __restrict__ pos, float* __restrict__ x0){
    long i = (long)blockIdx.x * 256 + threadIdx.x;
    long total = (long)B_ * NT_ * 768;
    if (i >= total) return;
    int d = (int)(i % 768); long rw = i / 768;
    int n = (int)(rw % NT_); int b = (int)(rw / NT_);
    float v;
    if (n == 0) v = cls[d] + pos[d];
    else        v = pe[((long)b * 196 + (n - 1)) * 768 + d] + pos[(long)n * 768 + d];
    x0[i] = v;
}

__global__ void copy_f(const float* __restrict__ a, float* __restrict__ b, long total){
    long i = (long)blockIdx.x * 256 + threadIdx.x;
    if (i < total) b[i] = a[i];
}

// ============ build sub-branch rows ============
__global__ void build_sub_k(const float* __restrict__ x0, const float* __restrict__ subp,
    const float* __restrict__ pos, float* __restrict__ xSub){
    long i = (long)blockIdx.x * 256 + threadIdx.x;
    long total = (long)B_ * NS_ * 768;
    if (i >= total) return;
    int d = (int)(i % 768); long rw = i / 768;
    int n = (int)(rw % NS_); int b = (int)(rw / NS_);
    float v;
    if (n == 0)      v = x0[((long)b * NT_) * 768 + d];
    else if (n <= 5) v = subp[(n - 1) * 768 + d] + pos[d];
    else             v = x0[((long)b * NT_ + (n - 5)) * 768 + d];
    xSub[i] = v;
}

// ============ routing (f64 internals) ============
__global__ __launch_bounds__(256) void select_k(
    const float* __restrict__ xA, const float* __restrict__ norm_w,
    const float* __restrict__ norm_b, const float* __restrict__ main_key,
    const float* __restrict__ sub_key, const int* __restrict__ task_id_p,
    int* __restrict__ selm, int* __restrict__ flag)
{
    __shared__ double red[4];
    int b = blockIdx.x, t = threadIdx.x, lane = t & 63, wid = t >> 6;
    const float* xr = xA + (long)b * NT_ * 768;
    double v0 = xr[t], v1 = xr[t + 256], v2 = xr[t + 512];
    double S = block_reduce_sum_d(v0 + v1 + v2, red, lane, wid);
    double m = S * (1.0 / 768.0);
    double d0 = v0 - m, d1 = v1 - m, d2 = v2 - m;
    double Q = block_reduce_sum_d(d0*d0 + d1*d1 + d2*d2, red, lane, wid);
    double rs = 1.0 / sqrt(Q * (1.0 / 768.0) + 1e-6);
    double q0 = d0 * rs * (double)norm_w[t]       + (double)norm_b[t];
    double q1 = d1 * rs * (double)norm_w[t + 256] + (double)norm_b[t + 256];
    double q2 = d2 * rs * (double)norm_w[t + 512] + (double)norm_b[t + 512];
    double qn = block_reduce_sum_d(q0*q0 + q1*q1 + q2*q2, red, lane, wid);
    double qinv = 1.0 / sqrt(fmax(qn, 1e-12));

    int tk = *task_id_p;
    int ncand = tk + 2;
    double best = -1e300; int bsel = 0;
    for (int c = 0; c < ncand; c++){
        const float* cr = (c <= tk) ? (main_key + (long)c * 768) : sub_key;
        double c0 = cr[t], c1 = cr[t + 256], c2 = cr[t + 512];
        double dotq = block_reduce_sum_d(q0*c0 + q1*c1 + q2*c2, red, lane, wid);
        double nc   = block_reduce_sum_d(c0*c0 + c1*c1 + c2*c2, red, lane, wid);
        double sim = dotq * qinv * (1.0 / sqrt(fmax(nc, 1e-12)));
        if (sim > best){ best = sim; bsel = c; }
    }
    if (t == 0){
        int isMain = (bsel <= tk) ? 1 : 0;
        selm[b] = isMain ? bsel : 0;
        flag[b] = isMain;
    }
}

// ============ final head (f64 internals, f32 out) ============
__global__ __launch_bounds__(256) void head_k(
    const float* __restrict__ xM, const float* __restrict__ xSub,
    const float* __restrict__ norm_w, const float* __restrict__ norm_b,
    const float* __restrict__ fc_w, const float* __restrict__ fc_b,
    const int* __restrict__ flag, float* __restrict__ out)
{
    __shared__ double vec[768];
    __shared__ double red[4];
    int b = blockIdx.x, t = threadIdx.x, lane = t & 63, wid = t >> 6;
    int isMain = flag[b];
    double a0 = 0.0, a1 = 0.0, a2 = 0.0;
    int nrows = isMain ? 1 : 5;
    for (int rI = 0; rI < nrows; rI++){
        const float* xr = isMain ? (xM + (long)b * NT_ * 768)
                                 : (xSub + ((long)b * NS_ + 1 + rI) * 768);
        double v0 = xr[t], v1 = xr[t + 256], v2 = xr[t + 512];
        double S = block_reduce_sum_d(v0 + v1 + v2, red, lane, wid);
        double m = S * (1.0 / 768.0);
        double d0 = v0 - m, d1 = v1 - m, d2 = v2 - m;
        double Q = block_reduce_sum_d(d0*d0 + d1*d1 + d2*d2, red, lane, wid);
        double rs = 1.0 / sqrt(Q * (1.0 / 768.0) + 1e-6);
        a0 += d0 * rs * (double)norm_w[t]       + (double)norm_b[t];
        a1 += d1 * rs * (double)norm_w[t + 256] + (double)norm_b[t + 256];
        a2 += d2 * rs * (double)norm_w[t + 512] + (double)norm_b[t + 512];
    }
    double scl = isMain ? 1.0 : 0.2;
    vec[t] = a0 * scl; vec[t + 256] = a1 * scl; vec[t + 512] = a2 * scl;
    __syncthreads();
    if (t < NCLS_){
        const float* wr = fc_w + (long)t * 768;
        double acc = (double)fc_b[t];
#pragma unroll 8
        for (int j = 0; j < 768; j++) acc += vec[j] * (double)wr[j];
        out[b * NCLS_ + t] = (float)acc;
    }
}

// ================= host-side =================
struct Params {
    const float *qkv_w, *qkv_b, *proj_w, *proj_b;
    const float *ln1_w, *ln1_b, *ln2_w, *ln2_b;
    const float *fc1_w, *fc1_b, *fc2_w, *fc2_b;
    const float *prompts; const int* selm;
    short *lnb, *attb, *hidb;
    float *qkvb;
    // bf16 weight cache (may be null)
    const short *qkv_wc, *proj_wc, *fc1_wc, *fc2_wc;
    bool cache;
};

template<int EPI>
static void launch_gemm(hipStream_t st, const short* A, const float* Wf, const short* Wc,
                        bool cache, const float* bias, const float* Res,
                        float* Cf, short* Cb, int M, int K, int N)
{
    dim3 g(N / 128, (M + 127) / 128);
    if (cache)
        gemm_bf16<EPI, 1><<<g, 256, 0, st>>>(A, (const void*)Wc, bias, Res, Cf, Cb, M, K, N);
    else
        gemm_bf16<EPI, 0><<<g, 256, 0, st>>>(A, (const void*)Wf, bias, Res, Cf, Cb, M, K, N);
}

// mode 0: concat (std attn both segments)  mode 1: main std  mode 2: main deep
static void run_layer(hipStream_t st, float* x, int M, int layer, int mode, int li,
                      const Params& P)
{
    ln_k<<<M, 256, 0, st>>>(x, P.ln1_w + layer * 768, P.ln1_b + layer * 768, P.lnb);
    launch_gemm<0>(st, P.lnb, P.qkv_w + (long)layer * 2304 * 768,
        P.qkv_wc + (P.cache ? (long)layer * 2304 * 768 : 0), P.cache,
        P.qkv_b + layer * 2304, nullptr, P.qkvb, nullptr, M, 768, 2304);
    if (mode == 0){
        attn_std_v3<<<dim3(B_ * HEADS_, 2), 512, 0, st>>>(
            P.qkvb, P.attb, NT_,
            P.qkvb + (long)MROW_ * 2304, P.attb + (long)MROW_ * 768, NS_);
    } else if (mode == 1){
        attn_std_v3<<<dim3(B_ * HEADS_, 1), 512, 0, st>>>(
            P.qkvb, P.attb, NT_, P.qkvb, P.attb, NT_);
    } else {
        attn_deep_v2<<<dim3(B_, NT_), 256, 0, st>>>(P.qkvb, P.prompts, P.selm, P.attb, li);
    }
    launch_gemm<2>(st, P.attb, P.proj_w + (long)layer * 768 * 768,
        P.proj_wc + (P.cache ? (long)layer * 768 * 768 : 0), P.cache,
        P.proj_b + layer * 768, x, x, nullptr, M, 768, 768);
    ln_k<<<M, 256, 0, st>>>(x, P.ln2_w + layer * 768, P.ln2_b + layer * 768, P.lnb);
    launch_gemm<1>(st, P.lnb, P.fc1_w + (long)layer * 3072 * 768,
        P.fc1_wc + (P.cache ? (long)layer * 3072 * 768 : 0), P.cache,
        P.fc1_b + layer * 3072, nullptr, nullptr, P.hidb, M, 768, 3072);
    launch_gemm<2>(st, P.hidb, P.fc2_w + (long)layer * 768 * 3072,
        P.fc2_wc + (P.cache ? (long)layer * 768 * 3072 : 0), P.cache,
        P.fc2_b + layer * 768, x, x, nullptr, M, 3072, 768);
}

extern "C" void kernel_launch(void* const* d_in, const int* in_sizes, int n_in,
                              void* d_out, int out_size, void* d_ws, size_t ws_size,
                              hipStream_t stream)
{
    (void)in_sizes; (void)n_in; (void)out_size;
    const float* inputs   = (const float*)d_in[0];
    const int*   task_id  = (const int*)  d_in[1];
    const float* patch_w  = (const float*)d_in[2];
    const float* patch_b  = (const float*)d_in[3];
    const float* cls_tok  = (const float*)d_in[4];
    const float* pos      = (const float*)d_in[5];
    const float* qkv_w    = (const float*)d_in[6];
    const float* qkv_b    = (const float*)d_in[7];
    const float* proj_w   = (const float*)d_in[8];
    const float* proj_b   = (const float*)d_in[9];
    const float* ln1_w    = (const float*)d_in[10];
    const float* ln1_b    = (const float*)d_in[11];
    const float* ln2_w    = (const float*)d_in[12];
    const float* ln2_b    = (const float*)d_in[13];
    const float* fc1_w    = (const float*)d_in[14];
    const float* fc1_b    = (const float*)d_in[15];
    const float* fc2_w    = (const float*)d_in[16];
    const float* fc2_b    = (const float*)d_in[17];
    const float* norm_w   = (const float*)d_in[18];
    const float* norm_b   = (const float*)d_in[19];
    const float* fc_w     = (const float*)d_in[20];
    const float* fc_b     = (const float*)d_in[21];
    const float* main_key = (const float*)d_in[22];
    const float* sub_key  = (const float*)d_in[23];
    const float* m_prompts= (const float*)d_in[24];
    const float* s_prompt = (const float*)d_in[25];
    float* out = (float*)d_out;

    char* wsb = (char*)d_ws;
    size_t off = 0;
    auto allocB = [&](size_t bytes) -> void* {
        void* p = (void*)(wsb + off);
        off += (bytes + 255) & ~(size_t)255;
        return p;
    };
    float* x0   = (float*)allocB((size_t)MROW_ * 768 * 4);
    float* xC   = (float*)allocB((size_t)CROW_ * 768 * 4);
    float* xM   = (float*)allocB((size_t)MROW_ * 768 * 4);
    short* lnb  = (short*)allocB((size_t)CROW_ * 768 * 2);
    short* attb = (short*)allocB((size_t)CROW_ * 768 * 2);
    float* qkvb = (float*)allocB((size_t)CROW_ * 2304 * 4);
    short* hidb = (short*)allocB((size_t)CROW_ * 3072 * 2);
    int*   selm = (int*)allocB(64);
    int*   flag = (int*)allocB(64);

    // optional bf16 weight cache (guarded by ws_size; deterministic host branch)
    const size_t nQkv = (size_t)DEPTH_ * 2304 * 768;
    const size_t nProj = (size_t)DEPTH_ * 768 * 768;
    const size_t nFc1 = (size_t)DEPTH_ * 3072 * 768;
    const size_t nFc2 = (size_t)DEPTH_ * 768 * 3072;
    const size_t nPatch = (size_t)768 * 768;
    size_t cacheBytes = (nQkv + nProj + nFc1 + nFc2 + nPatch) * 2 + 5 * 256;
    bool cache = (ws_size >= off + cacheBytes + (1u << 20));
    short *qkv_wc = nullptr, *proj_wc = nullptr, *fc1_wc = nullptr, *fc2_wc = nullptr, *patch_wc = nullptr;
    if (cache){
        qkv_wc  = (short*)allocB(nQkv * 2);
        proj_wc = (short*)allocB(nProj * 2);
        fc1_wc  = (short*)allocB(nFc1 * 2);
        fc2_wc  = (short*)allocB(nFc2 * 2);
        patch_wc= (short*)allocB(nPatch * 2);
        convert_w_k<<<2048, 256, 0, stream>>>(qkv_w,  qkv_wc,  (long)nQkv);
        convert_w_k<<<1024, 256, 0, stream>>>(proj_w, proj_wc, (long)nProj);
        convert_w_k<<<2048, 256, 0, stream>>>(fc1_w,  fc1_wc,  (long)nFc1);
        convert_w_k<<<2048, 256, 0, stream>>>(fc2_w,  fc2_wc,  (long)nFc2);
        convert_w_k<<<256,  256, 0, stream>>>(patch_w, patch_wc, (long)nPatch);
    }

    Params P;
    P.qkv_w = qkv_w; P.qkv_b = qkv_b; P.proj_w = proj_w; P.proj_b = proj_b;
    P.ln1_w = ln1_w; P.ln1_b = ln1_b; P.ln2_w = ln2_w; P.ln2_b = ln2_b;
    P.fc1_w = fc1_w; P.fc1_b = fc1_b; P.fc2_w = fc2_w; P.fc2_b = fc2_b;
    P.prompts = m_prompts; P.selm = selm;
    P.lnb = lnb; P.attb = attb; P.hidb = hidb; P.qkvb = qkvb;
    P.qkv_wc = qkv_wc; P.proj_wc = proj_wc; P.fc1_wc = fc1_wc; P.fc2_wc = fc2_wc;
    P.cache = cache;

    const long XN = (long)MROW_ * 768;

    // -------- patch embed --------
    {
        long tot = (long)B_ * 196 * 768;
        short* un  = hidb;
        float* peo = qkvb;
        unfold_k<<<(int)((tot + 255) / 256), 256, 0, stream>>>(inputs, un);
        launch_gemm<0>(stream, un, patch_w, patch_wc, cache, patch_b, nullptr,
                       peo, nullptr, 3136, 768, 768);
        assemble_k<<<(int)((XN + 255) / 256), 256, 0, stream>>>(peo, cls_tok, pos, x0);
        copy_f<<<(int)((XN + 255) / 256), 256, 0, stream>>>(x0, xC, XN);
        long st = (long)SROW_ * 768;
        build_sub_k<<<(int)((st + 255) / 256), 256, 0, stream>>>(x0, s_prompt, pos,
                                                                 xC + (long)MROW_ * 768);
    }

    // -------- concatenated pass A + sub branch --------
    for (int i = 0; i < DEPTH_; i++){
        run_layer(stream, xC, CROW_, i, 0, 0, P);
        if (i == 1)
            copy_f<<<(int)((XN + 255) / 256), 256, 0, stream>>>(xC, xM, XN);
    }

    // -------- routing --------
    select_k<<<16, 256, 0, stream>>>(xC, norm_w, norm_b, main_key, sub_key,
                                     task_id, selm, flag);

    // -------- main branch layers 2..11 (deep prompts at 2,3,4) --------
    for (int i = 2; i < DEPTH_; i++){
        int mode = (i >= 2 && i <= 4) ? 2 : 1;
        run_layer(stream, xM, MROW_, i, mode, i - 2, P);
    }

    // -------- heads + per-sample select --------
    head_k<<<16, 256, 0, stream>>>(xM, xC + (long)MROW_ * 768, norm_w, norm_b,
                                   fc_w, fc_b, flag, out);
}

// Round 9
// 6476.366 us; speedup vs baseline: 13.9319x; 1.4153x over previous
//
#include <hip/hip_runtime.h>
#include <math.h>

// ---------------- constants ----------------
#define B_    16
#define NT_   197
#define NS_   202
#define HEADS_ 12
#define DEPTH_ 12
#define NCLS_ 100
#define MROW_ (B_ * NT_)      // 3152
#define SROW_ (B_ * NS_)      // 3232
#define CROW_ (MROW_ + SROW_) // 6384

typedef __attribute__((ext_vector_type(8))) short short8v;
typedef __attribute__((ext_vector_type(4))) float f32x4;

// f32 -> bf16 bits (RNE)
__device__ __forceinline__ short f2bf(float f){
    unsigned u = __builtin_bit_cast(unsigned, f);
    unsigned r = (u + 0x7FFFu + ((u >> 16) & 1u)) >> 16;
    return (short)r;
}
__device__ __forceinline__ unsigned pk2(float a, float b){
    return (unsigned)(unsigned short)f2bf(a) | (((unsigned)(unsigned short)f2bf(b)) << 16);
}

// ============ float block reduce (256 thr) ============
__device__ __forceinline__ float block_reduce_sum_f(float s, float* red, int lane, int wid){
#pragma unroll
    for (int off = 32; off; off >>= 1) s += __shfl_xor(s, off);
    if (lane == 0) red[wid] = s;
    __syncthreads();
    float S = red[0] + red[1] + red[2] + red[3];
    __syncthreads();
    return S;
}
// ============ double block reduce (256 thr) — routing/head only ============
__device__ __forceinline__ double block_reduce_sum_d(double s, double* red, int lane, int wid){
#pragma unroll
    for (int off = 32; off; off >>= 1) s += __shfl_xor(s, off);
    if (lane == 0) red[wid] = s;
    __syncthreads();
    double S = red[0] + red[1] + red[2] + red[3];
    __syncthreads();
    return S;
}

// ============ weight convert f32 -> bf16 ============
__global__ void convert_w_k(const float* __restrict__ in, short* __restrict__ out, long n){
    long i = ((long)blockIdx.x * 256 + threadIdx.x) * 8;
    long stride = (long)gridDim.x * 256 * 8;
    for (; i < n; i += stride){
        float4 a = *(const float4*)(in + i);
        float4 b = *(const float4*)(in + i + 4);
        uint4 o4;
        o4.x = pk2(a.x, a.y); o4.y = pk2(a.z, a.w);
        o4.z = pk2(b.x, b.y); o4.w = pk2(b.z, b.w);
        *(uint4*)(out + i) = o4;
    }
}

// ============ bf16 MFMA GEMM (unchanged, verified) ============
template<int EPI, int WB>
__global__ __launch_bounds__(256) void gemm_bf16(
    const short* __restrict__ A, const void* __restrict__ Wv,
    const float* __restrict__ bias, const float* __restrict__ Res,
    float* __restrict__ Cf, short* __restrict__ Cb, int M, int K, int N)
{
    __shared__ short As[128 * 48];
    __shared__ short Bs[128 * 48];
    const int t = threadIdx.x;
    const int lane = t & 63, wid = t >> 6;
    const int wr = wid >> 1, wc = wid & 1;
    const long row0 = (long)blockIdx.y * 128;
    const long col0 = (long)blockIdx.x * 128;

    f32x4 acc[4][4];
#pragma unroll
    for (int i = 0; i < 4; i++)
#pragma unroll
        for (int j = 0; j < 4; j++) acc[i][j] = (f32x4){0.f, 0.f, 0.f, 0.f};

    const int l15 = lane & 15, lkg = lane >> 4;
    const int ar = t >> 2, ac = t & 3;
    const int bn = t >> 1, bh = t & 1;

    for (int k0 = 0; k0 < K; k0 += 32){
#pragma unroll
        for (int it = 0; it < 2; it++){
            int r = ar + it * 64;
            long gr = row0 + r;
            uint4 v = {0u, 0u, 0u, 0u};
            if (gr < M) v = *(const uint4*)(A + gr * K + k0 + ac * 8);
            *(uint4*)(&As[r * 48 + ac * 8]) = v;
        }
        if (WB == 1){
            const short* Wb = (const short*)Wv;
            const short* Wp = Wb + (col0 + bn) * K + k0 + bh * 16;
            uint4 lo = *(const uint4*)(Wp);
            uint4 hi = *(const uint4*)(Wp + 8);
            *(uint4*)(&Bs[bn * 48 + bh * 16])     = lo;
            *(uint4*)(&Bs[bn * 48 + bh * 16 + 8]) = hi;
        } else {
            const float* Wf = (const float*)Wv;
            const float* Wp = Wf + (col0 + bn) * K + k0 + bh * 16;
            unsigned rr[8];
#pragma unroll
            for (int g = 0; g < 8; g++){
                float2 f = *(const float2*)(Wp + g * 2);
                rr[g] = pk2(f.x, f.y);
            }
            uint4 lo = {rr[0], rr[1], rr[2], rr[3]};
            uint4 hi = {rr[4], rr[5], rr[6], rr[7]};
            *(uint4*)(&Bs[bn * 48 + bh * 16])     = lo;
            *(uint4*)(&Bs[bn * 48 + bh * 16 + 8]) = hi;
        }
        __syncthreads();

        short8v a[4], b[4];
#pragma unroll
        for (int i = 0; i < 4; i++)
            a[i] = *(const short8v*)(&As[(wr * 64 + i * 16 + l15) * 48 + lkg * 8]);
#pragma unroll
        for (int j = 0; j < 4; j++)
            b[j] = *(const short8v*)(&Bs[(wc * 64 + j * 16 + l15) * 48 + lkg * 8]);
#pragma unroll
        for (int i = 0; i < 4; i++)
#pragma unroll
            for (int j = 0; j < 4; j++)
                acc[i][j] = __builtin_amdgcn_mfma_f32_16x16x32_bf16(a[i], b[j], acc[i][j], 0, 0, 0);
        __syncthreads();
    }

#pragma unroll
    for (int i = 0; i < 4; i++){
#pragma unroll
        for (int q = 0; q < 4; q++){
            long gr = row0 + wr * 64 + i * 16 + lkg * 4 + q;
            if (gr >= M) continue;
#pragma unroll
            for (int j = 0; j < 4; j++){
                long gc = col0 + wc * 64 + j * 16 + l15;
                float v = acc[i][j][q] + bias[gc];
                if (EPI == 1){
                    v = 0.5f * v * (1.f + erff(v * 0.70710678118654752f));
                    Cb[gr * N + gc] = f2bf(v);
                } else if (EPI == 2){
                    Cf[gr * N + gc] = v + Res[gr * N + gc];
                } else {
                    Cf[gr * N + gc] = v;
                }
            }
        }
    }
}

// ============ LayerNorm (two-pass f32) : x f32 -> lnb bf16 ============
__global__ __launch_bounds__(256) void ln_k(const float* __restrict__ x,
    const float* __restrict__ w, const float* __restrict__ b,
    short* __restrict__ y)
{
    __shared__ float red[4];
    int row = blockIdx.x, t = threadIdx.x;
    int lane = t & 63, wid = t >> 6;
    const float* xr = x + (long)row * 768;
    float v0 = xr[t], v1 = xr[t + 256], v2 = xr[t + 512];
    float S = block_reduce_sum_f(v0 + v1 + v2, red, lane, wid);
    float m = S * (1.f / 768.f);
    float d0 = v0 - m, d1 = v1 - m, d2 = v2 - m;
    float Q = block_reduce_sum_f(d0*d0 + d1*d1 + d2*d2, red, lane, wid);
    float rs = 1.f / sqrtf(Q * (1.f / 768.f) + 1e-6f);
    short* yr = y + (long)row * 768;
    yr[t]       = f2bf(d0 * rs * w[t]       + b[t]);
    yr[t + 256] = f2bf(d1 * rs * w[t + 256] + b[t + 256]);
    yr[t + 512] = f2bf(d2 * rs * w[t + 512] + b[t + 512]);
}

// ============ std MHA via MFMA: one 512-thr block per (b,h) ============
// Keys pad to 208 (13x16); PV k-dim pads to 224 (7x32).
// K staged bf16 [208][72]; V staged TRANSPOSED bf16 [64][232]; P per-wave [16][232].
__global__ __launch_bounds__(512) void attn_mfma(
    const float* __restrict__ qkv0, short* __restrict__ o0, int N0,
    const float* __restrict__ qkv1, short* __restrict__ o1, int N1)
{
    __shared__ short Ks[208 * 72];
    __shared__ short Vs[64 * 232];
    __shared__ short Ps[8 * 16 * 232];
    const int bh = blockIdx.x;
    const int b = bh / HEADS_, h = bh % HEADS_;
    const int seg = blockIdx.y;
    const float* qkv = seg ? qkv1 : qkv0;
    short* o = seg ? o1 : o0;
    const int Ntok = seg ? N1 : N0;
    const int t = threadIdx.x, lane = t & 63, wid = t >> 6;
    const long rb = (long)b * Ntok;

    // ---- stage K (bf16 rows) + V (bf16 transposed) ----
    {
        const int r = t >> 2, c = (t & 3) * 16;
#pragma unroll
        for (int pass = 0; pass < 2; pass++){
            int m = r + pass * 128;
            if (m < 208){
                if (m < Ntok){
                    const float* kr = qkv + (rb + m) * 2304 + 768  + h * 64 + c;
                    const float* vr = qkv + (rb + m) * 2304 + 1536 + h * 64 + c;
#pragma unroll
                    for (int j = 0; j < 16; j += 4){
                        float4 f = *(const float4*)(kr + j);
                        *(unsigned*)(&Ks[m * 72 + c + j])     = pk2(f.x, f.y);
                        *(unsigned*)(&Ks[m * 72 + c + j + 2]) = pk2(f.z, f.w);
                    }
#pragma unroll
                    for (int j = 0; j < 16; j += 4){
                        float4 f = *(const float4*)(vr + j);
                        Vs[(c + j    ) * 232 + m] = f2bf(f.x);
                        Vs[(c + j + 1) * 232 + m] = f2bf(f.y);
                        Vs[(c + j + 2) * 232 + m] = f2bf(f.z);
                        Vs[(c + j + 3) * 232 + m] = f2bf(f.w);
                    }
                } else {
#pragma unroll
                    for (int j = 0; j < 16; j += 2)
                        *(unsigned*)(&Ks[m * 72 + c + j]) = 0u;
#pragma unroll
                    for (int j = 0; j < 16; j++)
                        Vs[(c + j) * 232 + m] = 0;
                }
            }
        }
        // V pad: m in [208,224)
        for (int i = t; i < 64 * 16; i += 512){
            int d = i >> 4, m = 208 + (i & 15);
            Vs[d * 232 + m] = 0;
        }
        // P pad cols [208,224) for all 8 waves
        for (int i = t; i < 8 * 16 * 16; i += 512){
            int w = i >> 8, rr = (i >> 4) & 15, m = 208 + (i & 15);
            Ps[(w * 16 + rr) * 232 + m] = 0;
        }
    }
    __syncthreads();

    const int l15 = lane & 15, lkg = lane >> 4;
    short* Pw = &Ps[wid * 16 * 232];

    for (int s = wid; s < 13; s += 8){
        const int q0 = s * 16;
        // ---- Q frags direct from global (scale 0.125 folded; exact pow2) ----
        short8v a0, a1;
        {
            int qrow = q0 + l15;
            if (qrow < Ntok){
                const float* qp = qkv + (rb + qrow) * 2304 + h * 64;
                float4 f0 = *(const float4*)(qp + lkg * 8);
                float4 f1 = *(const float4*)(qp + lkg * 8 + 4);
                float4 f2 = *(const float4*)(qp + 32 + lkg * 8);
                float4 f3 = *(const float4*)(qp + 32 + lkg * 8 + 4);
                unsigned u0 = pk2(f0.x * 0.125f, f0.y * 0.125f);
                unsigned u1 = pk2(f0.z * 0.125f, f0.w * 0.125f);
                unsigned u2 = pk2(f1.x * 0.125f, f1.y * 0.125f);
                unsigned u3 = pk2(f1.z * 0.125f, f1.w * 0.125f);
                unsigned v0 = pk2(f2.x * 0.125f, f2.y * 0.125f);
                unsigned v1 = pk2(f2.z * 0.125f, f2.w * 0.125f);
                unsigned v2 = pk2(f3.x * 0.125f, f3.y * 0.125f);
                unsigned v3 = pk2(f3.z * 0.125f, f3.w * 0.125f);
                uint4 ua = {u0, u1, u2, u3}, ub = {v0, v1, v2, v3};
                a0 = __builtin_bit_cast(short8v, ua);
                a1 = __builtin_bit_cast(short8v, ub);
            } else {
                uint4 z = {0u,0u,0u,0u};
                a0 = __builtin_bit_cast(short8v, z);
                a1 = __builtin_bit_cast(short8v, z);
            }
        }
        // ---- QK^T: 13 key tiles x K=64 (2 chunks) ----
        f32x4 sacc[13];
#pragma unroll
        for (int j = 0; j < 13; j++){
            short8v b0 = *(const short8v*)(&Ks[(j * 16 + l15) * 72 + lkg * 8]);
            short8v b1 = *(const short8v*)(&Ks[(j * 16 + l15) * 72 + 32 + lkg * 8]);
            f32x4 z = {0.f, 0.f, 0.f, 0.f};
            z = __builtin_amdgcn_mfma_f32_16x16x32_bf16(a0, b0, z, 0, 0, 0);
            z = __builtin_amdgcn_mfma_f32_16x16x32_bf16(a1, b1, z, 0, 0, 0);
            sacc[j] = z;
        }
        // ---- mask invalid keys ----
#pragma unroll
        for (int j = 0; j < 13; j++){
            if (j * 16 + l15 >= Ntok){
                sacc[j][0] = -1e30f; sacc[j][1] = -1e30f;
                sacc[j][2] = -1e30f; sacc[j][3] = -1e30f;
            }
        }
        // ---- softmax per row (row = lkg*4+rr; cols spread over l15 x 13 tiles) ----
#pragma unroll
        for (int rr = 0; rr < 4; rr++){
            float mx = sacc[0][rr];
#pragma unroll
            for (int j = 1; j < 13; j++) mx = fmaxf(mx, sacc[j][rr]);
            mx = fmaxf(mx, __shfl_xor(mx, 1));
            mx = fmaxf(mx, __shfl_xor(mx, 2));
            mx = fmaxf(mx, __shfl_xor(mx, 4));
            mx = fmaxf(mx, __shfl_xor(mx, 8));
            float pv[13];
            float sum = 0.f;
#pragma unroll
            for (int j = 0; j < 13; j++){
                float e = expf(sacc[j][rr] - mx);
                pv[j] = e; sum += e;
            }
            sum += __shfl_xor(sum, 1);
            sum += __shfl_xor(sum, 2);
            sum += __shfl_xor(sum, 4);
            sum += __shfl_xor(sum, 8);
            float inv = 1.f / sum;
#pragma unroll
            for (int j = 0; j < 13; j++)
                Pw[(lkg * 4 + rr) * 232 + j * 16 + l15] = f2bf(pv[j] * inv);
        }
        // ---- PV: A = P frags (same-wave LDS round-trip), B = V^T frags ----
        short8v pa[7];
#pragma unroll
        for (int kc = 0; kc < 7; kc++)
            pa[kc] = *(const short8v*)(&Pw[l15 * 232 + kc * 32 + lkg * 8]);
#pragma unroll
        for (int dj = 0; dj < 4; dj++){
            f32x4 oacc = {0.f, 0.f, 0.f, 0.f};
#pragma unroll
            for (int kc = 0; kc < 7; kc++){
                short8v vb = *(const short8v*)(&Vs[(dj * 16 + l15) * 232 + kc * 32 + lkg * 8]);
                oacc = __builtin_amdgcn_mfma_f32_16x16x32_bf16(pa[kc], vb, oacc, 0, 0, 0);
            }
#pragma unroll
            for (int rr = 0; rr < 4; rr++){
                int q = q0 + lkg * 4 + rr;
                if (q < Ntok)
                    o[(rb + q) * 768 + h * 64 + dj * 16 + l15] = f2bf(oacc[rr]);
            }
        }
    }
}

// ============ deep attention v2 (unchanged, verified) ============
__global__ __launch_bounds__(256) void attn_deep_v2(
    const float* __restrict__ qkv, const float* __restrict__ prompts,
    const int* __restrict__ selm, short* __restrict__ o, int li)
{
    __shared__ float q[768];
    __shared__ float sc[256];
    __shared__ float red[256];
    const int b = blockIdx.x, n = blockIdx.y, t = threadIdx.x;
    const int lane = t & 63, w = t >> 6;
    const float* qr = qkv + (long)(b * NT_ + n) * 2304;
    q[t] = qr[t]; q[t + 256] = qr[t + 256]; q[t + 512] = qr[t + 512];
    __syncthreads();

    const float4 q0 = *(const float4*)(&q[lane * 4]);
    const float4 q1 = *(const float4*)(&q[256 + lane * 4]);
    const float4 q2 = *(const float4*)(&q[512 + lane * 4]);

    const float* kp = prompts + ((long)selm[b] * 6 + 2 * li) * 5 * 768;
    const float* vp = kp + 5 * 768;

    for (int m = w; m < 202; m += 4){
        const float* kr = (m < 5) ? (kp + (long)m * 768)
                                  : (qkv + (long)(b * NT_ + (m - 5)) * 2304 + 768);
        float4 k0 = *(const float4*)(kr + lane * 4);
        float4 k1 = *(const float4*)(kr + 256 + lane * 4);
        float4 k2 = *(const float4*)(kr + 512 + lane * 4);
        float a = q0.x*k0.x + q0.y*k0.y + q0.z*k0.z + q0.w*k0.w
                + q1.x*k1.x + q1.y*k1.y + q1.z*k1.z + q1.w*k1.w
                + q2.x*k2.x + q2.y*k2.y + q2.z*k2.z + q2.w*k2.w;
#pragma unroll
        for (int off = 32; off; off >>= 1) a += __shfl_xor(a, off);
        if (lane == 0) sc[m] = a * 0.125f;
    }
    __syncthreads();

    float s = (t < 202) ? sc[t] : -1e30f;
    red[t] = s; __syncthreads();
    for (int wd = 128; wd; wd >>= 1){ if (t < wd) red[t] = fmaxf(red[t], red[t+wd]); __syncthreads(); }
    float mx = red[0]; __syncthreads();
    float e = (t < 202) ? expf(s - mx) : 0.f;
    red[t] = e; __syncthreads();
    for (int wd = 128; wd; wd >>= 1){ if (t < wd) red[t] += red[t+wd]; __syncthreads(); }
    float inv = 1.f / red[0];
    __syncthreads();
    sc[t] = e * inv;
    __syncthreads();

    float a0 = 0.f, a1 = 0.f, a2 = 0.f;
    for (int m = 0; m < 5; m++){
        const float* vr = vp + (long)m * 768;
        float pm = sc[m];
        a0 += pm * vr[t]; a1 += pm * vr[t + 256]; a2 += pm * vr[t + 512];
    }
    for (int m = 5; m < 202; m++){
        const float* vr = qkv + (long)(b * NT_ + (m - 5)) * 2304 + 1536;
        float pm = sc[m];
        a0 += pm * vr[t]; a1 += pm * vr[t + 256]; a2 += pm * vr[t + 512];
    }
    short* ob = o + (long)b * NT_ * 768 + n;
    ob[(long)t * 197]         = f2bf(a0);
    ob[(long)(t + 256) * 197] = f2bf(a1);
    ob[(long)(t + 512) * 197] = f2bf(a2);
}

// ============ patch unfold (f32 -> bf16) ============
__global__ void unfold_k(const float* __restrict__ in, short* __restrict__ out){
    long i = (long)blockIdx.x * 256 + threadIdx.x;
    long total = (long)B_ * 196 * 768;
    if (i >= total) return;
    int f = (int)(i % 768); long rw = i / 768;
    int t = (int)(rw % 196); int b = (int)(rw / 196);
    int gy = t / 14, gx = t % 14;
    int c = f >> 8, rem = f & 255, py = rem >> 4, px = rem & 15;
    out[i] = f2bf(in[(((long)(b * 3 + c) * 224) + gy * 16 + py) * 224 + gx * 16 + px]);
}

// ============ assemble x0 = [cls+pos ; patches+pos] (f32) ============
__global__ void assemble_k(const float* __restrict__ pe, const float* __restrict__ cls,
    const float* __restrict__ pos, float* __restrict__ x0){
    long i = (long)blockIdx.x * 256 + threadIdx.x;
    long total = (long)B_ * NT_ * 768;
    if (i >= total) return;
    int d = (int)(i % 768); long rw = i / 768;
    int n = (int)(rw % NT_); int b = (int)(rw / NT_);
    float v;
    if (n == 0) v = cls[d] + pos[d];
    else        v = pe[((long)b * 196 + (n - 1)) * 768 + d] + pos[(long)n * 768 + d];
    x0[i] = v;
}

__global__ void copy_f(const float* __restrict__ a, float* __restrict__ b, long total){
    long i = (long)blockIdx.x * 256 + threadIdx.x;
    if (i < total) b[i] = a[i];
}

// ============ build sub-branch rows ============
__global__ void build_sub_k(const float* __restrict__ x0, const float* __restrict__ subp,
    const float* __restrict__ pos, float* __restrict__ xSub){
    long i = (long)blockIdx.x * 256 + threadIdx.x;
    long total = (long)B_ * NS_ * 768;
    if (i >= total) return;
    int d = (int)(i % 768); long rw = i / 768;
    int n = (int)(rw % NS_); int b = (int)(rw / NS_);
    float v;
    if (n == 0)      v = x0[((long)b * NT_) * 768 + d];
    else if (n <= 5) v = subp[(n - 1) * 768 + d] + pos[d];
    else             v = x0[((long)b * NT_ + (n - 5)) * 768 + d];
    xSub[i] = v;
}

// ============ routing (f64 internals) ============
__global__ __launch_bounds__(256) void select_k(
    const float* __restrict__ xA, const float* __restrict__ norm_w,
    const float* __restrict__ norm_b, const float* __restrict__ main_key,
    const float* __restrict__ sub_key, const int* __restrict__ task_id_p,
    int* __restrict__ selm, int* __restrict__ flag)
{
    __shared__ double red[4];
    int b = blockIdx.x, t = threadIdx.x, lane = t & 63, wid = t >> 6;
    const float* xr = xA + (long)b * NT_ * 768;
    double v0 = xr[t], v1 = xr[t + 256], v2 = xr[t + 512];
    double S = block_reduce_sum_d(v0 + v1 + v2, red, lane, wid);
    double m = S * (1.0 / 768.0);
    double d0 = v0 - m, d1 = v1 - m, d2 = v2 - m;
    double Q = block_reduce_sum_d(d0*d0 + d1*d1 + d2*d2, red, lane, wid);
    double rs = 1.0 / sqrt(Q * (1.0 / 768.0) + 1e-6);
    double q0 = d0 * rs * (double)norm_w[t]       + (double)norm_b[t];
    double q1 = d1 * rs * (double)norm_w[t + 256] + (double)norm_b[t + 256];
    double q2 = d2 * rs * (double)norm_w[t + 512] + (double)norm_b[t + 512];
    double qn = block_reduce_sum_d(q0*q0 + q1*q1 + q2*q2, red, lane, wid);
    double qinv = 1.0 / sqrt(fmax(qn, 1e-12));

    int tk = *task_id_p;
    int ncand = tk + 2;
    double best = -1e300; int bsel = 0;
    for (int c = 0; c < ncand; c++){
        const float* cr = (c <= tk) ? (main_key + (long)c * 768) : sub_key;
        double c0 = cr[t], c1 = cr[t + 256], c2 = cr[t + 512];
        double dotq = block_reduce_sum_d(q0*c0 + q1*c1 + q2*c2, red, lane, wid);
        double nc   = block_reduce_sum_d(c0*c0 + c1*c1 + c2*c2, red, lane, wid);
        double sim = dotq * qinv * (1.0 / sqrt(fmax(nc, 1e-12)));
        if (sim > best){ best = sim; bsel = c; }
    }
    if (t == 0){
        int isMain = (bsel <= tk) ? 1 : 0;
        selm[b] = isMain ? bsel : 0;
        flag[b] = isMain;
    }
}

// ============ final head (f64 internals, f32 out) ============
__global__ __launch_bounds__(256) void head_k(
    const float* __restrict__ xM, const float* __restrict__ xSub,
    const float* __restrict__ norm_w, const float* __restrict__ norm_b,
    const float* __restrict__ fc_w, const float* __restrict__ fc_b,
    const int* __restrict__ flag, float* __restrict__ out)
{
    __shared__ double vec[768];
    __shared__ double red[4];
    int b = blockIdx.x, t = threadIdx.x, lane = t & 63, wid = t >> 6;
    int isMain = flag[b];
    double a0 = 0.0, a1 = 0.0, a2 = 0.0;
    int nrows = isMain ? 1 : 5;
    for (int rI = 0; rI < nrows; rI++){
        const float* xr = isMain ? (xM + (long)b * NT_ * 768)
                                 : (xSub + ((long)b * NS_ + 1 + rI) * 768);
        double v0 = xr[t], v1 = xr[t + 256], v2 = xr[t + 512];
        double S = block_reduce_sum_d(v0 + v1 + v2, red, lane, wid);
        double m = S * (1.0 / 768.0);
        double d0 = v0 - m, d1 = v1 - m, d2 = v2 - m;
        double Q = block_reduce_sum_d(d0*d0 + d1*d1 + d2*d2, red, lane, wid);
        double rs = 1.0 / sqrt(Q * (1.0 / 768.0) + 1e-6);
        a0 += d0 * rs * (double)norm_w[t]       + (double)norm_b[t];
        a1 += d1 * rs * (double)norm_w[t + 256] + (double)norm_b[t + 256];
        a2 += d2 * rs * (double)norm_w[t + 512] + (double)norm_b[t + 512];
    }
    double scl = isMain ? 1.0 : 0.2;
    vec[t] = a0 * scl; vec[t + 256] = a1 * scl; vec[t + 512] = a2 * scl;
    __syncthreads();
    if (t < NCLS_){
        const float* wr = fc_w + (long)t * 768;
        double acc = (double)fc_b[t];
#pragma unroll 8
        for (int j = 0; j < 768; j++) acc += vec[j] * (double)wr[j];
        out[b * NCLS_ + t] = (float)acc;
    }
}

// ================= host-side =================
struct Params {
    const float *qkv_w, *qkv_b, *proj_w, *proj_b;
    const float *ln1_w, *ln1_b, *ln2_w, *ln2_b;
    const float *fc1_w, *fc1_b, *fc2_w, *fc2_b;
    const float *prompts; const int* selm;
    short *lnb, *attb, *hidb;
    float *qkvb;
    const short *qkv_wc, *proj_wc, *fc1_wc, *fc2_wc;
    bool cache;
};

template<int EPI>
static void launch_gemm(hipStream_t st, const short* A, const float* Wf, const short* Wc,
                        bool cache, const float* bias, const float* Res,
                        float* Cf, short* Cb, int M, int K, int N)
{
    dim3 g(N / 128, (M + 127) / 128);
    if (cache)
        gemm_bf16<EPI, 1><<<g, 256, 0, st>>>(A, (const void*)Wc, bias, Res, Cf, Cb, M, K, N);
    else
        gemm_bf16<EPI, 0><<<g, 256, 0, st>>>(A, (const void*)Wf, bias, Res, Cf, Cb, M, K, N);
}

// mode 0: concat (std attn both segments)  mode 1: main std  mode 2: main deep
static void run_layer(hipStream_t st, float* x, int M, int layer, int mode, int li,
                      const Params& P)
{
    ln_k<<<M, 256, 0, st>>>(x, P.ln1_w + layer * 768, P.ln1_b + layer * 768, P.lnb);
    launch_gemm<0>(st, P.lnb, P.qkv_w + (long)layer * 2304 * 768,
        P.qkv_wc + (P.cache ? (long)layer * 2304 * 768 : 0), P.cache,
        P.qkv_b + layer * 2304, nullptr, P.qkvb, nullptr, M, 768, 2304);
    if (mode == 0){
        attn_mfma<<<dim3(B_ * HEADS_, 2), 512, 0, st>>>(
            P.qkvb, P.attb, NT_,
            P.qkvb + (long)MROW_ * 2304, P.attb + (long)MROW_ * 768, NS_);
    } else if (mode == 1){
        attn_mfma<<<dim3(B_ * HEADS_, 1), 512, 0, st>>>(
            P.qkvb, P.attb, NT_, P.qkvb, P.attb, NT_);
    } else {
        attn_deep_v2<<<dim3(B_, NT_), 256, 0, st>>>(P.qkvb, P.prompts, P.selm, P.attb, li);
    }
    launch_gemm<2>(st, P.attb, P.proj_w + (long)layer * 768 * 768,
        P.proj_wc + (P.cache ? (long)layer * 768 * 768 : 0), P.cache,
        P.proj_b + layer * 768, x, x, nullptr, M, 768, 768);
    ln_k<<<M, 256, 0, st>>>(x, P.ln2_w + layer * 768, P.ln2_b + layer * 768, P.lnb);
    launch_gemm<1>(st, P.lnb, P.fc1_w + (long)layer * 3072 * 768,
        P.fc1_wc + (P.cache ? (long)layer * 3072 * 768 : 0), P.cache,
        P.fc1_b + layer * 3072, nullptr, nullptr, P.hidb, M, 768, 3072);
    launch_gemm<2>(st, P.hidb, P.fc2_w + (long)layer * 768 * 3072,
        P.fc2_wc + (P.cache ? (long)layer * 768 * 3072 : 0), P.cache,
        P.fc2_b + layer * 768, x, x, nullptr, M, 3072, 768);
}

extern "C" void kernel_launch(void* const* d_in, const int* in_sizes, int n_in,
                              void* d_out, int out_size, void* d_ws, size_t ws_size,
                              hipStream_t stream)
{
    (void)in_sizes; (void)n_in; (void)out_size;
    const float* inputs   = (const float*)d_in[0];
    const int*   task_id  = (const int*)  d_in[1];
    const float* patch_w  = (const float*)d_in[2];
    const float* patch_b  = (const float*)d_in[3];
    const float* cls_tok  = (const float*)d_in[4];
    const float* pos      = (const float*)d_in[5];
    const float* qkv_w    = (const float*)d_in[6];
    const float* qkv_b    = (const float*)d_in[7];
    const float* proj_w   = (const float*)d_in[8];
    const float* proj_b   = (const float*)d_in[9];
    const float* ln1_w    = (const float*)d_in[10];
    const float* ln1_b    = (const float*)d_in[11];
    const float* ln2_w    = (const float*)d_in[12];
    const float* ln2_b    = (const float*)d_in[13];
    const float* fc1_w    = (const float*)d_in[14];
    const float* fc1_b    = (const float*)d_in[15];
    const float* fc2_w    = (const float*)d_in[16];
    const float* fc2_b    = (const float*)d_in[17];
    const float* norm_w   = (const float*)d_in[18];
    const float* norm_b   = (const float*)d_in[19];
    const float* fc_w     = (const float*)d_in[20];
    const float* fc_b     = (const float*)d_in[21];
    const float* main_key = (const float*)d_in[22];
    const float* sub_key  = (const float*)d_in[23];
    const float* m_prompts= (const float*)d_in[24];
    const float* s_prompt = (const float*)d_in[25];
    float* out = (float*)d_out;

    char* wsb = (char*)d_ws;
    size_t off = 0;
    auto allocB = [&](size_t bytes) -> void* {
        void* p = (void*)(wsb + off);
        off += (bytes + 255) & ~(size_t)255;
        return p;
    };
    float* x0   = (float*)allocB((size_t)MROW_ * 768 * 4);
    float* xC   = (float*)allocB((size_t)CROW_ * 768 * 4);
    float* xM   = (float*)allocB((size_t)MROW_ * 768 * 4);
    short* lnb  = (short*)allocB((size_t)CROW_ * 768 * 2);
    short* attb = (short*)allocB((size_t)CROW_ * 768 * 2);
    float* qkvb = (float*)allocB((size_t)CROW_ * 2304 * 4);
    short* hidb = (short*)allocB((size_t)CROW_ * 3072 * 2);
    int*   selm = (int*)allocB(64);
    int*   flag = (int*)allocB(64);

    // optional bf16 weight cache (guarded by ws_size)
    const size_t nQkv = (size_t)DEPTH_ * 2304 * 768;
    const size_t nProj = (size_t)DEPTH_ * 768 * 768;
    const size_t nFc1 = (size_t)DEPTH_ * 3072 * 768;
    const size_t nFc2 = (size_t)DEPTH_ * 768 * 3072;
    const size_t nPatch = (size_t)768 * 768;
    size_t cacheBytes = (nQkv + nProj + nFc1 + nFc2 + nPatch) * 2 + 5 * 256;
    bool cache = (ws_size >= off + cacheBytes + (1u << 20));
    short *qkv_wc = nullptr, *proj_wc = nullptr, *fc1_wc = nullptr, *fc2_wc = nullptr, *patch_wc = nullptr;
    if (cache){
        qkv_wc  = (short*)allocB(nQkv * 2);
        proj_wc = (short*)allocB(nProj * 2);
        fc1_wc  = (short*)allocB(nFc1 * 2);
        fc2_wc  = (short*)allocB(nFc2 * 2);
        patch_wc= (short*)allocB(nPatch * 2);
        convert_w_k<<<2048, 256, 0, stream>>>(qkv_w,  qkv_wc,  (long)nQkv);
        convert_w_k<<<1024, 256, 0, stream>>>(proj_w, proj_wc, (long)nProj);
        convert_w_k<<<2048, 256, 0, stream>>>(fc1_w,  fc1_wc,  (long)nFc1);
        convert_w_k<<<2048, 256, 0, stream>>>(fc2_w,  fc2_wc,  (long)nFc2);
        convert_w_k<<<256,  256, 0, stream>>>(patch_w, patch_wc, (long)nPatch);
    }

    Params P;
    P.qkv_w = qkv_w; P.qkv_b = qkv_b; P.proj_w = proj_w; P.proj_b = proj_b;
    P.ln1_w = ln1_w; P.ln1_b = ln1_b; P.ln2_w = ln2_w; P.ln2_b = ln2_b;
    P.fc1_w = fc1_w; P.fc1_b = fc1_b; P.fc2_w = fc2_w; P.fc2_b = fc2_b;
    P.prompts = m_prompts; P.selm = selm;
    P.lnb = lnb; P.attb = attb; P.hidb = hidb; P.qkvb = qkvb;
    P.qkv_wc = qkv_wc; P.proj_wc = proj_wc; P.fc1_wc = fc1_wc; P.fc2_wc = fc2_wc;
    P.cache = cache;

    const long XN = (long)MROW_ * 768;

    // -------- patch embed --------
    {
        long tot = (long)B_ * 196 * 768;
        short* un  = hidb;
        float* peo = qkvb;
        unfold_k<<<(int)((tot + 255) / 256), 256, 0, stream>>>(inputs, un);
        launch_gemm<0>(stream, un, patch_w, patch_wc, cache, patch_b, nullptr,
                       peo, nullptr, 3136, 768, 768);
        assemble_k<<<(int)((XN + 255) / 256), 256, 0, stream>>>(peo, cls_tok, pos, x0);
        copy_f<<<(int)((XN + 255) / 256), 256, 0, stream>>>(x0, xC, XN);
        long st = (long)SROW_ * 768;
        build_sub_k<<<(int)((st + 255) / 256), 256, 0, stream>>>(x0, s_prompt, pos,
                                                                 xC + (long)MROW_ * 768);
    }

    // -------- concatenated pass A + sub branch --------
    for (int i = 0; i < DEPTH_; i++){
        run_layer(stream, xC, CROW_, i, 0, 0, P);
        if (i == 1)
            copy_f<<<(int)((XN + 255) / 256), 256, 0, stream>>>(xC, xM, XN);
    }

    // -------- routing --------
    select_k<<<16, 256, 0, stream>>>(xC, norm_w, norm_b, main_key, sub_key,
                                     task_id, selm, flag);

    // -------- main branch layers 2..11 (deep prompts at 2,3,4) --------
    for (int i = 2; i < DEPTH_; i++){
        int mode = (i >= 2 && i <= 4) ? 2 : 1;
        run_layer(stream, xM, MROW_, i, mode, i - 2, P);
    }

    // -------- heads + per-sample select --------
    head_k<<<16, 256, 0, stream>>>(xM, xC + (long)MROW_ * 768, norm_w, norm_b,
                                   fc_w, fc_b, flag, out);
}